// Round 5
// baseline (385.182 us; speedup 1.0000x reference)
//
#include <hip/hip_runtime.h>
#include <hip/hip_bf16.h>
#include <stdint.h>

#define N_NODES 102400
#define N_EDGES 409600
#define N_GRAPHS 2048
#define MAXN 64

typedef __attribute__((ext_vector_type(8))) short short8;
typedef __attribute__((ext_vector_type(4))) float f32x4;

static __device__ __forceinline__ float bfu2f(unsigned short u) {
    union { unsigned int i; float f; } v;
    v.i = ((unsigned int)u) << 16;
    return v.f;
}
static __device__ __forceinline__ unsigned short f2bfu(float f) {
    __hip_bfloat16 h = __float2bfloat16(f);
    return *reinterpret_cast<unsigned short*>(&h);
}

// ---------------- degree / CSR build ----------------

__global__ void deg_kernel(const int* __restrict__ dst, int* __restrict__ deg) {
    int e = blockIdx.x * blockDim.x + threadIdx.x;
    if (e < N_EDGES) atomicAdd(&deg[dst[e]], 1);
}

__global__ void dinv_kernel(const int* __restrict__ deg, float* __restrict__ dinv) {
    int i = blockIdx.x * blockDim.x + threadIdx.x;
    if (i < N_NODES) dinv[i] = rsqrtf((float)deg[i] + 1.0f);
}

__global__ void scan1_kernel(const int* __restrict__ deg, int* __restrict__ excl,
                             int* __restrict__ bsum) {
    __shared__ int sh[1024];
    int tid = threadIdx.x;
    int gid = blockIdx.x * 1024 + tid;   // N = 100*1024 exactly
    int v = deg[gid];
    sh[tid] = v;
    __syncthreads();
    for (int off = 1; off < 1024; off <<= 1) {
        int t = (tid >= off) ? sh[tid - off] : 0;
        __syncthreads();
        sh[tid] += t;
        __syncthreads();
    }
    excl[gid] = sh[tid] - v;
    if (tid == 1023) bsum[blockIdx.x] = sh[tid];
}

__global__ void scan2_kernel(int* __restrict__ bsum) {  // 100 entries
    __shared__ int sh[128];
    int tid = threadIdx.x;
    int v = (tid < 100) ? bsum[tid] : 0;
    sh[tid] = v;
    __syncthreads();
    for (int off = 1; off < 128; off <<= 1) {
        int t = (tid >= off) ? sh[tid - off] : 0;
        __syncthreads();
        sh[tid] += t;
        __syncthreads();
    }
    if (tid < 100) bsum[tid] = sh[tid] - v;
}

__global__ void scan3_kernel(const int* __restrict__ excl, const int* __restrict__ bsum,
                             int* __restrict__ offs, int* __restrict__ cursor) {
    int gid = blockIdx.x * blockDim.x + threadIdx.x;
    if (gid < N_NODES) {
        int o = excl[gid] + bsum[gid >> 10];
        offs[gid] = o;
        cursor[gid] = o;
    }
    if (gid == 0) offs[N_NODES] = N_EDGES;
}

__global__ void fill_kernel(const int* __restrict__ src, const int* __restrict__ dst,
                            int* __restrict__ cursor, int* __restrict__ csr_src,
                            float* __restrict__ csr_w, const float* __restrict__ dinv) {
    int e = blockIdx.x * blockDim.x + threadIdx.x;
    if (e >= N_EDGES) return;
    int s = src[e], d = dst[e];
    int pos = atomicAdd(&cursor[d], 1);
    csr_src[pos] = s;
    csr_w[pos] = dinv[s] * dinv[d];
}

// ---------------- to_dense_batch row mapping ----------------

__global__ void start_kernel(const int* __restrict__ batch, int* __restrict__ startb) {
    int i = blockIdx.x * blockDim.x + threadIdx.x;
    if (i >= N_NODES) return;
    if (i == 0 || batch[i] != batch[i - 1]) startb[batch[i]] = i;
    if (i == 0) startb[N_GRAPHS] = N_NODES;
}

__global__ void rowmap_kernel(const int* __restrict__ batch, const int* __restrict__ startb,
                              const int* __restrict__ pmax, int* __restrict__ rowmap) {
    int i = blockIdx.x * blockDim.x + threadIdx.x;
    if (i >= N_NODES) return;
    int b = batch[i];
    int mx = *pmax;
    int pos = i - startb[b];
    rowmap[i] = (pos < mx) ? (b * mx + pos) : -1;
}

// zero only the padding rows of the dense output: rows (b, pos) with pos >= count[b]
__global__ void padzero_kernel(const int* __restrict__ startb, float* __restrict__ out) {
    int b = blockIdx.y;
    int idx = blockIdx.x * blockDim.x + threadIdx.x;  // covers MAXN*100 float2
    int pos = idx / 100;
    int f = idx - pos * 100;
    int count = startb[b + 1] - startb[b];
    if (pos >= count && pos < MAXN) {
        float2 z = {0.0f, 0.0f};
        *(float2*)(out + ((size_t)b * MAXN + pos) * 200 + f * 2) = z;
    }
}

// ---------------- weight prep ----------------

__global__ void prep_w_kernel(const float* __restrict__ W, const float* __restrict__ b,
                              int K, int Nc, int Kp, int Na,
                              __hip_bfloat16* __restrict__ WT, float* __restrict__ bp) {
    int i = blockIdx.x * blockDim.x + threadIdx.x;
    int total = Na * Kp;
    if (i < total) {
        int c = i / Kp, k = i - c * Kp;
        float v = (c < Nc && k < K) ? W[k * Nc + c] : 0.0f;
        WT[i] = __float2bfloat16(v);
    }
    if (i < Na) bp[i] = (i < Nc) ? b[i] : 0.0f;
}

// ---------------- aggregation: thread-per-(node, chunk), 4-way edge unroll ----------

// Layer 1: X fp32 [N,78] -> out bf16 [N,96]. C=48 chunks of 2 cols.
__global__ __launch_bounds__(256) void agg_f32_v2(
    const float* __restrict__ X,
    const int* __restrict__ offs, const int* __restrict__ csr_src,
    const float* __restrict__ csr_w, const float* __restrict__ dinv,
    __hip_bfloat16* __restrict__ out) {
    constexpr int C = 48;
    int idx = blockIdx.x * blockDim.x + threadIdx.x;
    if (idx >= N_NODES * C) return;
    int node = idx / C;
    int c = idx - node * C;
    int col = c * 2;
    float a0 = 0.0f, a1 = 0.0f;
    if (col < 78) {
        float di = dinv[node];
        float sw = di * di;
        const float* Xr = X + (size_t)node * 78 + col;
        float2 h = *(const float2*)Xr;
        a0 = sw * h.x;
        a1 = sw * h.y;
        int e0 = offs[node], e1 = offs[node + 1];
        int j = e0;
        for (; j + 4 <= e1; j += 4) {
            int s0 = csr_src[j], s1 = csr_src[j + 1], s2 = csr_src[j + 2], s3 = csr_src[j + 3];
            float w0 = csr_w[j], w1 = csr_w[j + 1], w2 = csr_w[j + 2], w3 = csr_w[j + 3];
            float2 v0 = *(const float2*)(X + (size_t)s0 * 78 + col);
            float2 v1 = *(const float2*)(X + (size_t)s1 * 78 + col);
            float2 v2 = *(const float2*)(X + (size_t)s2 * 78 + col);
            float2 v3 = *(const float2*)(X + (size_t)s3 * 78 + col);
            a0 += w0 * v0.x + w1 * v1.x + w2 * v2.x + w3 * v3.x;
            a1 += w0 * v0.y + w1 * v1.y + w2 * v2.y + w3 * v3.y;
        }
        for (; j < e1; ++j) {
            int s = csr_src[j];
            float w = csr_w[j];
            float2 v = *(const float2*)(X + (size_t)s * 78 + col);
            a0 += w * v.x;
            a1 += w * v.y;
        }
    }
    __hip_bfloat162 r;
    r.x = __float2bfloat16(a0);
    r.y = __float2bfloat16(a1);
    *(__hip_bfloat162*)(out + (size_t)node * 96 + col) = r;
}

// Layers 2/3: H bf16 [N,LD] -> out bf16 [N,LD]. C=LD/4 chunks of 4 cols.
template <int LD>
__global__ __launch_bounds__(256) void agg_bf16_v2(
    const __hip_bfloat16* __restrict__ H,
    const int* __restrict__ offs, const int* __restrict__ csr_src,
    const float* __restrict__ csr_w, const float* __restrict__ dinv,
    __hip_bfloat16* __restrict__ out) {
    constexpr int C = LD / 4;
    int idx = blockIdx.x * blockDim.x + threadIdx.x;
    if (idx >= N_NODES * C) return;
    int node = idx / C;
    int c = idx - node * C;
    const unsigned short* Hu = (const unsigned short*)H;
    size_t rowoff = (size_t)node * LD + c * 4;
    float di = dinv[node];
    float sw = di * di;
    ushort4 h = *(const ushort4*)(Hu + rowoff);
    float a0 = sw * bfu2f(h.x), a1 = sw * bfu2f(h.y), a2 = sw * bfu2f(h.z), a3 = sw * bfu2f(h.w);
    int e0 = offs[node], e1 = offs[node + 1];
    int j = e0;
    for (; j + 4 <= e1; j += 4) {
        int s0 = csr_src[j], s1 = csr_src[j + 1], s2 = csr_src[j + 2], s3 = csr_src[j + 3];
        float w0 = csr_w[j], w1 = csr_w[j + 1], w2 = csr_w[j + 2], w3 = csr_w[j + 3];
        ushort4 v0 = *(const ushort4*)(Hu + (size_t)s0 * LD + c * 4);
        ushort4 v1 = *(const ushort4*)(Hu + (size_t)s1 * LD + c * 4);
        ushort4 v2 = *(const ushort4*)(Hu + (size_t)s2 * LD + c * 4);
        ushort4 v3 = *(const ushort4*)(Hu + (size_t)s3 * LD + c * 4);
        a0 += w0 * bfu2f(v0.x) + w1 * bfu2f(v1.x) + w2 * bfu2f(v2.x) + w3 * bfu2f(v3.x);
        a1 += w0 * bfu2f(v0.y) + w1 * bfu2f(v1.y) + w2 * bfu2f(v2.y) + w3 * bfu2f(v3.y);
        a2 += w0 * bfu2f(v0.z) + w1 * bfu2f(v1.z) + w2 * bfu2f(v2.z) + w3 * bfu2f(v3.z);
        a3 += w0 * bfu2f(v0.w) + w1 * bfu2f(v1.w) + w2 * bfu2f(v2.w) + w3 * bfu2f(v3.w);
    }
    for (; j < e1; ++j) {
        int s = csr_src[j];
        float w = csr_w[j];
        ushort4 v = *(const ushort4*)(Hu + (size_t)s * LD + c * 4);
        a0 += w * bfu2f(v.x);
        a1 += w * bfu2f(v.y);
        a2 += w * bfu2f(v.z);
        a3 += w * bfu2f(v.w);
    }
    ushort4 r;
    r.x = f2bfu(a0);
    r.y = f2bfu(a1);
    r.z = f2bfu(a2);
    r.w = f2bfu(a3);
    *(ushort4*)((unsigned short*)out + rowoff) = r;
}

// ---------------- barrier-free streaming MFMA GEMM ----------------
// Each wave independently computes a 64x64 tile: C[r0:r0+64, c0:c0+64] =
// A[r0:r0+64, :K] @ WT[c0:c0+64, :K]^T. A and B fragments are loaded straight
// from global to registers (16B dwordx4 per lane, MFMA-native layout); W strips
// are tiny and stay L2-resident. No LDS, no barriers; K fully unrolled with a
// named 2-deep register double-buffer (all indices compile-time).
// Wave->tile map is col-strip-fastest so a block's 4 waves share A rows.

template <int NSTEPS>
__global__ __launch_bounds__(256) void gemm_stream(
    const __hip_bfloat16* __restrict__ A,      // [N_NODES, NSTEPS*32] bf16
    const __hip_bfloat16* __restrict__ WT,     // [>=cstrips*64, NSTEPS*32] bf16
    const float* __restrict__ biasp,
    void* __restrict__ Cout, int ldc, int ccols, int cstrips,
    const int* __restrict__ rowmap, int relu) {
    constexpr int LDA = NSTEPS * 32;
    const int lane = threadIdx.x & 63;
    const int wave = blockIdx.x * 4 + (threadIdx.x >> 6);
    const int cstrip = wave % cstrips;
    const int rtile = wave / cstrips;
    if (rtile >= N_NODES / 64) return;
    const int r0 = rtile * 64;
    const int c0 = cstrip * 64;

    // fragment base pointers: lane holds row (lane&15) of its 16-row group,
    // k-bytes [(lane>>4)*16, +16) of each 64B k-step chunk.
    const int frow = lane & 15;
    const int kb0 = (lane >> 4) << 3;  // element offset (8 bf16 = 16B)
    const __hip_bfloat16* ab[4];
    const __hip_bfloat16* bb[4];
#pragma unroll
    for (int m = 0; m < 4; ++m) ab[m] = A + (size_t)(r0 + m * 16 + frow) * LDA + kb0;
#pragma unroll
    for (int n = 0; n < 4; ++n) bb[n] = WT + (size_t)(c0 + n * 16 + frow) * LDA + kb0;

    f32x4 acc[4][4];
#pragma unroll
    for (int m = 0; m < 4; ++m)
#pragma unroll
        for (int n = 0; n < 4; ++n) {
            f32x4 z = {0.0f, 0.0f, 0.0f, 0.0f};
            acc[m][n] = z;
        }

    short8 af[2][4], bfr[2][4];
#pragma unroll
    for (int m = 0; m < 4; ++m) af[0][m] = *(const short8*)(ab[m]);
#pragma unroll
    for (int n = 0; n < 4; ++n) bfr[0][n] = *(const short8*)(bb[n]);

#pragma unroll
    for (int t = 0; t < NSTEPS; ++t) {
        constexpr int unusedwarn = 0; (void)unusedwarn;
        const int cur = t & 1;
        const int nxt = cur ^ 1;
        if (t + 1 < NSTEPS) {
#pragma unroll
            for (int m = 0; m < 4; ++m) af[nxt][m] = *(const short8*)(ab[m] + (t + 1) * 32);
#pragma unroll
            for (int n = 0; n < 4; ++n) bfr[nxt][n] = *(const short8*)(bb[n] + (t + 1) * 32);
        }
#pragma unroll
        for (int m = 0; m < 4; ++m)
#pragma unroll
            for (int n = 0; n < 4; ++n)
                acc[m][n] = __builtin_amdgcn_mfma_f32_16x16x32_bf16(af[cur][m], bfr[cur][n],
                                                                    acc[m][n], 0, 0, 0);
    }

    // epilogue: C frag layout col=lane&15, row=(lane>>4)*4+j
    const int crow0 = r0 + ((lane >> 4) << 2);
    const int ccol0 = c0 + (lane & 15);
#pragma unroll
    for (int n = 0; n < 4; ++n) {
        int col = ccol0 + n * 16;
        if (col >= ccols) continue;
        float bv = biasp[col];
#pragma unroll
        for (int m = 0; m < 4; ++m) {
#pragma unroll
            for (int j = 0; j < 4; ++j) {
                int row = crow0 + m * 16 + j;
                float v = acc[m][n][j] + bv;
                if (relu) v = fmaxf(v, 0.0f);
                if (rowmap) {
                    int drow = rowmap[row];
                    if (drow >= 0) ((float*)Cout)[(size_t)drow * ldc + col] = v;
                } else {
                    ((__hip_bfloat16*)Cout)[(size_t)row * ldc + col] = __float2bfloat16(v);
                }
            }
        }
    }
}

// ---------------- launch ----------------

static inline char* align256(char* p) {
    return (char*)(((uintptr_t)p + 255) & ~(uintptr_t)255);
}

extern "C" void kernel_launch(void* const* d_in, const int* in_sizes, int n_in,
                              void* d_out, int out_size, void* d_ws, size_t ws_size,
                              hipStream_t stream) {
    const int N = N_NODES, E = N_EDGES;
    const float* x = (const float*)d_in[0];
    const int* ei = (const int*)d_in[1];
    const int* src = ei;
    const int* dst = ei + E;
    const int* batch = (const int*)d_in[2];
    const int* pmax = (const int*)d_in[3];
    const float* W1 = (const float*)d_in[4];
    const float* b1 = (const float*)d_in[5];
    const float* W2 = (const float*)d_in[6];
    const float* b2 = (const float*)d_in[7];
    const float* W3 = (const float*)d_in[8];
    const float* b3 = (const float*)d_in[9];
    const float* Wfc = (const float*)d_in[10];
    const float* bfc = (const float*)d_in[11];
    float* out = (float*)d_out;

    char* p = (char*)d_ws;
    float* dinv = (float*)p;          p = align256(p + (size_t)N * 4);
    int* deg = (int*)p;               p = align256(p + (size_t)N * 4);
    int* offs = (int*)p;              p = align256(p + (size_t)(N + 1) * 4);
    int* cursor = (int*)p;            p = align256(p + (size_t)N * 4);
    int* excl = (int*)p;              p = align256(p + (size_t)N * 4);
    int* bsum = (int*)p;              p = align256(p + 128 * 4);
    int* csr_src = (int*)p;           p = align256(p + (size_t)E * 4);
    float* csr_w = (float*)p;         p = align256(p + (size_t)E * 4);
    int* startb = (int*)p;            p = align256(p + (size_t)(N_GRAPHS + 1) * 4);
    int* rowmap = (int*)p;            p = align256(p + (size_t)N * 4);
    __hip_bfloat16* WT1 = (__hip_bfloat16*)p;  p = align256(p + 128 * 96 * 2);
    float* b1p = (float*)p;           p = align256(p + 128 * 4);
    __hip_bfloat16* WT2 = (__hip_bfloat16*)p;  p = align256(p + 256 * 96 * 2);
    float* b2p = (float*)p;           p = align256(p + 256 * 4);
    __hip_bfloat16* WT3 = (__hip_bfloat16*)p;  p = align256(p + 384 * 160 * 2);
    float* b3p = (float*)p;           p = align256(p + 384 * 4);
    __hip_bfloat16* WTF = (__hip_bfloat16*)p;  p = align256(p + 256 * 320 * 2);
    float* bFp = (float*)p;           p = align256(p + 256 * 4);
    __hip_bfloat16* bufAgg = (__hip_bfloat16*)p;  p = align256(p + (size_t)N * 320 * 2);
    __hip_bfloat16* bufH = (__hip_bfloat16*)p;    p = align256(p + (size_t)N * 320 * 2);

    // degree + CSR
    hipMemsetAsync(deg, 0, (size_t)N * 4, stream);
    deg_kernel<<<(E + 255) / 256, 256, 0, stream>>>(dst, deg);
    dinv_kernel<<<(N + 255) / 256, 256, 0, stream>>>(deg, dinv);
    scan1_kernel<<<100, 1024, 0, stream>>>(deg, excl, bsum);
    scan2_kernel<<<1, 128, 0, stream>>>(bsum);
    scan3_kernel<<<(N + 255) / 256, 256, 0, stream>>>(excl, bsum, offs, cursor);
    fill_kernel<<<(E + 255) / 256, 256, 0, stream>>>(src, dst, cursor, csr_src, csr_w, dinv);

    // dense-batch mapping
    start_kernel<<<(N + 255) / 256, 256, 0, stream>>>(batch, startb);
    rowmap_kernel<<<(N + 255) / 256, 256, 0, stream>>>(batch, startb, pmax, rowmap);

    // weight prep
    prep_w_kernel<<<(128 * 96 + 255) / 256, 256, 0, stream>>>(W1, b1, 78, 78, 96, 128, WT1, b1p);
    prep_w_kernel<<<(256 * 96 + 255) / 256, 256, 0, stream>>>(W2, b2, 78, 156, 96, 256, WT2, b2p);
    prep_w_kernel<<<(384 * 160 + 255) / 256, 256, 0, stream>>>(W3, b3, 156, 312, 160, 384, WT3, b3p);
    prep_w_kernel<<<(256 * 320 + 255) / 256, 256, 0, stream>>>(Wfc, bfc, 312, 200, 320, 256, WTF, bFp);

    const int RT = N / 64;  // 1600 row tiles

    // Layer 1: agg(x) -> [N,96]; gemm (K=96, 96 cols -> 2 strips)
    agg_f32_v2<<<(N * 48 + 255) / 256, 256, 0, stream>>>(x, offs, csr_src, csr_w, dinv, bufAgg);
    gemm_stream<3><<<RT * 2 / 4, 256, 0, stream>>>(
        bufAgg, WT1, b1p, bufH, 96, 96, 2, nullptr, 1);

    // Layer 2: agg -> [N,96]; gemm (K=96, 160 cols -> 3 strips)
    agg_bf16_v2<96><<<(N * 24 + 255) / 256, 256, 0, stream>>>(bufH, offs, csr_src, csr_w, dinv, bufAgg);
    gemm_stream<3><<<RT * 3 / 4, 256, 0, stream>>>(
        bufAgg, WT2, b2p, bufH, 160, 160, 3, nullptr, 1);

    // Layer 3: agg -> [N,160]; gemm (K=160, 320 cols -> 5 strips)
    agg_bf16_v2<160><<<(N * 40 + 255) / 256, 256, 0, stream>>>(bufH, offs, csr_src, csr_w, dinv, bufAgg);
    gemm_stream<5><<<RT * 5 / 4, 256, 0, stream>>>(
        bufAgg, WT3, b3p, bufH, 320, 320, 5, nullptr, 1);

    // FC + fused scatter (K=320, 200 cols -> 4 strips); zero only padding rows
    padzero_kernel<<<dim3(25, N_GRAPHS), 256, 0, stream>>>(startb, out);
    gemm_stream<10><<<RT * 4 / 4, 256, 0, stream>>>(
        bufH, WTF, bFp, out, 200, 200, 4, rowmap, 0);
}

// Round 6
// 338.419 us; speedup vs baseline: 1.1382x; 1.1382x over previous
//
#include <hip/hip_runtime.h>
#include <hip/hip_bf16.h>
#include <stdint.h>

#define N_NODES 102400
#define N_EDGES 409600
#define N_GRAPHS 2048
#define MAXN 64

typedef __attribute__((ext_vector_type(8))) short short8;
typedef __attribute__((ext_vector_type(4))) float f32x4;

static __device__ __forceinline__ float bfu2f(unsigned short u) {
    union { unsigned int i; float f; } v;
    v.i = ((unsigned int)u) << 16;
    return v.f;
}
static __device__ __forceinline__ unsigned short f2bfu(float f) {
    __hip_bfloat16 h = __float2bfloat16(f);
    return *reinterpret_cast<unsigned short*>(&h);
}

static __device__ __forceinline__ void gload16(const void* g, void* l) {
    __builtin_amdgcn_global_load_lds((const __attribute__((address_space(1))) void*)g,
                                     (__attribute__((address_space(3))) void*)l, 16, 0, 0);
}

// ---------------- degree / CSR build ----------------

__global__ void deg_kernel(const int* __restrict__ dst, int* __restrict__ deg) {
    int e = blockIdx.x * blockDim.x + threadIdx.x;
    if (e < N_EDGES) atomicAdd(&deg[dst[e]], 1);
}

__global__ void dinv_kernel(const int* __restrict__ deg, float* __restrict__ dinv) {
    int i = blockIdx.x * blockDim.x + threadIdx.x;
    if (i < N_NODES) dinv[i] = rsqrtf((float)deg[i] + 1.0f);
}

__global__ void scan1_kernel(const int* __restrict__ deg, int* __restrict__ excl,
                             int* __restrict__ bsum) {
    __shared__ int sh[1024];
    int tid = threadIdx.x;
    int gid = blockIdx.x * 1024 + tid;   // N = 100*1024 exactly
    int v = deg[gid];
    sh[tid] = v;
    __syncthreads();
    for (int off = 1; off < 1024; off <<= 1) {
        int t = (tid >= off) ? sh[tid - off] : 0;
        __syncthreads();
        sh[tid] += t;
        __syncthreads();
    }
    excl[gid] = sh[tid] - v;
    if (tid == 1023) bsum[blockIdx.x] = sh[tid];
}

__global__ void scan2_kernel(int* __restrict__ bsum) {  // 100 entries
    __shared__ int sh[128];
    int tid = threadIdx.x;
    int v = (tid < 100) ? bsum[tid] : 0;
    sh[tid] = v;
    __syncthreads();
    for (int off = 1; off < 128; off <<= 1) {
        int t = (tid >= off) ? sh[tid - off] : 0;
        __syncthreads();
        sh[tid] += t;
        __syncthreads();
    }
    if (tid < 100) bsum[tid] = sh[tid] - v;
}

__global__ void scan3_kernel(const int* __restrict__ excl, const int* __restrict__ bsum,
                             int* __restrict__ offs, int* __restrict__ cursor) {
    int gid = blockIdx.x * blockDim.x + threadIdx.x;
    if (gid < N_NODES) {
        int o = excl[gid] + bsum[gid >> 10];
        offs[gid] = o;
        cursor[gid] = o;
    }
    if (gid == 0) offs[N_NODES] = N_EDGES;
}

__global__ void fill_kernel(const int* __restrict__ src, const int* __restrict__ dst,
                            int* __restrict__ cursor, int* __restrict__ csr_src,
                            float* __restrict__ csr_w, const float* __restrict__ dinv) {
    int e = blockIdx.x * blockDim.x + threadIdx.x;
    if (e >= N_EDGES) return;
    int s = src[e], d = dst[e];
    int pos = atomicAdd(&cursor[d], 1);
    csr_src[pos] = s;
    csr_w[pos] = dinv[s] * dinv[d];
}

// ---------------- to_dense_batch row mapping ----------------

__global__ void start_kernel(const int* __restrict__ batch, int* __restrict__ startb) {
    int i = blockIdx.x * blockDim.x + threadIdx.x;
    if (i >= N_NODES) return;
    if (i == 0 || batch[i] != batch[i - 1]) startb[batch[i]] = i;
    if (i == 0) startb[N_GRAPHS] = N_NODES;
}

__global__ void rowmap_kernel(const int* __restrict__ batch, const int* __restrict__ startb,
                              const int* __restrict__ pmax, int* __restrict__ rowmap) {
    int i = blockIdx.x * blockDim.x + threadIdx.x;
    if (i >= N_NODES) return;
    int b = batch[i];
    int mx = *pmax;
    int pos = i - startb[b];
    rowmap[i] = (pos < mx) ? (b * mx + pos) : -1;
}

// zero only the padding rows of the dense output: rows (b, pos) with pos >= count[b]
__global__ void padzero_kernel(const int* __restrict__ startb, float* __restrict__ out) {
    int b = blockIdx.y;
    int idx = blockIdx.x * blockDim.x + threadIdx.x;  // covers MAXN*100 float2
    int pos = idx / 100;
    int f = idx - pos * 100;
    int count = startb[b + 1] - startb[b];
    if (pos >= count && pos < MAXN) {
        float2 z = {0.0f, 0.0f};
        *(float2*)(out + ((size_t)b * MAXN + pos) * 200 + f * 2) = z;
    }
}

// ---------------- weight prep ----------------

__global__ void prep_w_kernel(const float* __restrict__ W, const float* __restrict__ b,
                              int K, int Nc, int Kp, int Na,
                              __hip_bfloat16* __restrict__ WT, float* __restrict__ bp) {
    int i = blockIdx.x * blockDim.x + threadIdx.x;
    int total = Na * Kp;
    if (i < total) {
        int c = i / Kp, k = i - c * Kp;
        float v = (c < Nc && k < K) ? W[k * Nc + c] : 0.0f;
        WT[i] = __float2bfloat16(v);
    }
    if (i < Na) bp[i] = (i < Nc) ? b[i] : 0.0f;
}

// ---------------- aggregation: thread-per-(node, chunk), 4-way edge unroll ----------

__global__ __launch_bounds__(256) void agg_f32_v2(
    const float* __restrict__ X,
    const int* __restrict__ offs, const int* __restrict__ csr_src,
    const float* __restrict__ csr_w, const float* __restrict__ dinv,
    __hip_bfloat16* __restrict__ out) {
    constexpr int C = 48;
    int idx = blockIdx.x * blockDim.x + threadIdx.x;
    if (idx >= N_NODES * C) return;
    int node = idx / C;
    int c = idx - node * C;
    int col = c * 2;
    float a0 = 0.0f, a1 = 0.0f;
    if (col < 78) {
        float di = dinv[node];
        float sw = di * di;
        const float* Xr = X + (size_t)node * 78 + col;
        float2 h = *(const float2*)Xr;
        a0 = sw * h.x;
        a1 = sw * h.y;
        int e0 = offs[node], e1 = offs[node + 1];
        int j = e0;
        for (; j + 4 <= e1; j += 4) {
            int s0 = csr_src[j], s1 = csr_src[j + 1], s2 = csr_src[j + 2], s3 = csr_src[j + 3];
            float w0 = csr_w[j], w1 = csr_w[j + 1], w2 = csr_w[j + 2], w3 = csr_w[j + 3];
            float2 v0 = *(const float2*)(X + (size_t)s0 * 78 + col);
            float2 v1 = *(const float2*)(X + (size_t)s1 * 78 + col);
            float2 v2 = *(const float2*)(X + (size_t)s2 * 78 + col);
            float2 v3 = *(const float2*)(X + (size_t)s3 * 78 + col);
            a0 += w0 * v0.x + w1 * v1.x + w2 * v2.x + w3 * v3.x;
            a1 += w0 * v0.y + w1 * v1.y + w2 * v2.y + w3 * v3.y;
        }
        for (; j < e1; ++j) {
            int s = csr_src[j];
            float w = csr_w[j];
            float2 v = *(const float2*)(X + (size_t)s * 78 + col);
            a0 += w * v.x;
            a1 += w * v.y;
        }
    }
    __hip_bfloat162 r;
    r.x = __float2bfloat16(a0);
    r.y = __float2bfloat16(a1);
    *(__hip_bfloat162*)(out + (size_t)node * 96 + col) = r;
}

template <int LD>
__global__ __launch_bounds__(256) void agg_bf16_v2(
    const __hip_bfloat16* __restrict__ H,
    const int* __restrict__ offs, const int* __restrict__ csr_src,
    const float* __restrict__ csr_w, const float* __restrict__ dinv,
    __hip_bfloat16* __restrict__ out) {
    constexpr int C = LD / 4;
    int idx = blockIdx.x * blockDim.x + threadIdx.x;
    if (idx >= N_NODES * C) return;
    int node = idx / C;
    int c = idx - node * C;
    const unsigned short* Hu = (const unsigned short*)H;
    size_t rowoff = (size_t)node * LD + c * 4;
    float di = dinv[node];
    float sw = di * di;
    ushort4 h = *(const ushort4*)(Hu + rowoff);
    float a0 = sw * bfu2f(h.x), a1 = sw * bfu2f(h.y), a2 = sw * bfu2f(h.z), a3 = sw * bfu2f(h.w);
    int e0 = offs[node], e1 = offs[node + 1];
    int j = e0;
    for (; j + 4 <= e1; j += 4) {
        int s0 = csr_src[j], s1 = csr_src[j + 1], s2 = csr_src[j + 2], s3 = csr_src[j + 3];
        float w0 = csr_w[j], w1 = csr_w[j + 1], w2 = csr_w[j + 2], w3 = csr_w[j + 3];
        ushort4 v0 = *(const ushort4*)(Hu + (size_t)s0 * LD + c * 4);
        ushort4 v1 = *(const ushort4*)(Hu + (size_t)s1 * LD + c * 4);
        ushort4 v2 = *(const ushort4*)(Hu + (size_t)s2 * LD + c * 4);
        ushort4 v3 = *(const ushort4*)(Hu + (size_t)s3 * LD + c * 4);
        a0 += w0 * bfu2f(v0.x) + w1 * bfu2f(v1.x) + w2 * bfu2f(v2.x) + w3 * bfu2f(v3.x);
        a1 += w0 * bfu2f(v0.y) + w1 * bfu2f(v1.y) + w2 * bfu2f(v2.y) + w3 * bfu2f(v3.y);
        a2 += w0 * bfu2f(v0.z) + w1 * bfu2f(v1.z) + w2 * bfu2f(v2.z) + w3 * bfu2f(v3.z);
        a3 += w0 * bfu2f(v0.w) + w1 * bfu2f(v1.w) + w2 * bfu2f(v2.w) + w3 * bfu2f(v3.w);
    }
    for (; j < e1; ++j) {
        int s = csr_src[j];
        float w = csr_w[j];
        ushort4 v = *(const ushort4*)(Hu + (size_t)s * LD + c * 4);
        a0 += w * bfu2f(v.x);
        a1 += w * bfu2f(v.y);
        a2 += w * bfu2f(v.z);
        a3 += w * bfu2f(v.w);
    }
    ushort4 r;
    r.x = f2bfu(a0);
    r.y = f2bfu(a1);
    r.z = f2bfu(a2);
    r.w = f2bfu(a3);
    *(ushort4*)((unsigned short*)out + rowoff) = r;
}

// ---------------- bf16 MFMA GEMM (R4 structure: global_load_lds, depth-3, counted vmcnt) ----

__global__ __launch_bounds__(256) void mfma_gemm_kernel(
    const __hip_bfloat16* __restrict__ A, int lda,
    const __hip_bfloat16* __restrict__ WT,
    const float* __restrict__ biasp, int nsteps,
    void* __restrict__ Cout, int ldc, int ccols,
    const int* __restrict__ rowmap, int relu) {
    __shared__ __align__(16) char lds[49152];  // 3 x 16KB

    const int tid = threadIdx.x;
    const int lane = tid & 63;
    const int wid = tid >> 6;
    const int wr = wid >> 1, wc = wid & 1;
    const int r0 = blockIdx.y * 128;
    const int c0 = blockIdx.x * 128;

    const bool isB = (wid >= 2);
    const int half = wid & 1;
    const int srow = half * 64 + (lane >> 2);
    const size_t ldabytes = (size_t)lda * 2;
    const char* gbase = isB ? (const char*)(WT + (size_t)(c0 + srow) * lda)
                            : (const char*)(A + (size_t)(r0 + srow) * lda);
    gbase += (lane & 3) << 4;
    char* lbase = lds + (isB ? 8192 : 0) + half * 4096;

#define STAGE(s, b)                                                            \
    do {                                                                       \
        const char* g_ = gbase + (size_t)(s) * 64;                             \
        char* l_ = lbase + (b) * 16384;                                        \
        gload16(g_, l_);                                                       \
        gload16(g_ + 16 * ldabytes, l_ + 1024);                                \
        gload16(g_ + 32 * ldabytes, l_ + 2048);                                \
        gload16(g_ + 48 * ldabytes, l_ + 3072);                                \
    } while (0)

    const int frow = lane & 15;
    const int fsl = (lane >> 4) << 4;
    int aoff[4], boff[4];
#pragma unroll
    for (int m = 0; m < 4; ++m) aoff[m] = (wr * 64 + m * 16 + frow) * 64 + fsl;
#pragma unroll
    for (int n = 0; n < 4; ++n) boff[n] = 8192 + (wc * 64 + n * 16 + frow) * 64 + fsl;

    f32x4 acc[4][4];
#pragma unroll
    for (int m = 0; m < 4; ++m)
#pragma unroll
        for (int n = 0; n < 4; ++n) {
            f32x4 z = {0.0f, 0.0f, 0.0f, 0.0f};
            acc[m][n] = z;
        }

#define COMPUTE(b)                                                                        \
    do {                                                                                  \
        const char* cb_ = lds + (b) * 16384;                                              \
        short8 af[4], bfr[4];                                                             \
        _Pragma("unroll") for (int m = 0; m < 4; ++m) af[m] = *(const short8*)(cb_ + aoff[m]); \
        _Pragma("unroll") for (int n = 0; n < 4; ++n) bfr[n] = *(const short8*)(cb_ + boff[n]); \
        _Pragma("unroll") for (int m = 0; m < 4; ++m)                                     \
            _Pragma("unroll") for (int n = 0; n < 4; ++n)                                 \
                acc[m][n] = __builtin_amdgcn_mfma_f32_16x16x32_bf16(af[m], bfr[n], acc[m][n], 0, 0, 0); \
    } while (0)

    STAGE(0, 0);
    STAGE(1, 1);
    int t = 0;
    for (; t < nsteps - 1; ++t) {
        asm volatile("s_waitcnt vmcnt(4)" ::: "memory");
        __builtin_amdgcn_s_barrier();
        __builtin_amdgcn_sched_barrier(0);
        if (t + 2 < nsteps) STAGE(t + 2, (t + 2) % 3);
        COMPUTE(t % 3);
        __builtin_amdgcn_sched_barrier(0);
    }
    asm volatile("s_waitcnt vmcnt(0)" ::: "memory");
    __builtin_amdgcn_s_barrier();
    __builtin_amdgcn_sched_barrier(0);
    COMPUTE(t % 3);
#undef STAGE
#undef COMPUTE

    const int crow0 = r0 + wr * 64 + ((lane >> 4) << 2);
    const int ccol0 = c0 + wc * 64 + (lane & 15);
#pragma unroll
    for (int n = 0; n < 4; ++n) {
        int col = ccol0 + n * 16;
        if (col >= ccols) continue;
        float bv = biasp[col];
#pragma unroll
        for (int m = 0; m < 4; ++m) {
#pragma unroll
            for (int j = 0; j < 4; ++j) {
                int row = crow0 + m * 16 + j;
                float v = acc[m][n][j] + bv;
                if (relu) v = fmaxf(v, 0.0f);
                if (rowmap) {
                    int drow = rowmap[row];
                    if (drow >= 0) ((float*)Cout)[(size_t)drow * ldc + col] = v;
                } else {
                    ((__hip_bfloat16*)Cout)[(size_t)row * ldc + col] = __float2bfloat16(v);
                }
            }
        }
    }
}

// ---------------- fused layer3-GEMM + FC: h3 stays in LDS ----------------
// Block = 128 rows, 512 threads (8 waves).
// Stage 1: h3[128][320] = relu(A[128][160] @ W3T^T + b3) -> LDS (bf16, XOR-swizzled).
//   Wave w -> tile (rh=w>>2, cq=w&3): rows rh*64..+64, cols cq*80..+80.
//   A/B frags straight from global (A rows contiguous, W3T L2-hot).
// Stage 2: out[128][200] = h3 @ WTF^T + bFp, rowmap scatter.
//   Wave w -> tile rows (w>>2)*64, cols (w&3)*64 (cols >=200 guarded).
// Swizzle: byte ^= (row&7)<<4 within each 640B row -> stage-2 ds_read_b128 ~2-way.

__global__ __launch_bounds__(512) void gemm3fc_kernel(
    const __hip_bfloat16* __restrict__ A,     // [N,160] bf16 (agg of h2)
    const __hip_bfloat16* __restrict__ W3T,   // [384,160] bf16
    const float* __restrict__ b3p,            // [384]
    const __hip_bfloat16* __restrict__ WTF,   // [256,320] bf16
    const float* __restrict__ bFp,            // [256]
    float* __restrict__ out,
    const int* __restrict__ rowmap) {
    __shared__ __align__(16) char h3[128 * 640];  // 80 KB
    const int tid = threadIdx.x;
    const int lane = tid & 63;
    const int w = tid >> 6;
    const int r0 = blockIdx.x * 128;
    const int frow = lane & 15;
    const int kq = lane >> 4;  // 0..3
    const int rh = w >> 2;
    const int cq = w & 3;

    // ---- stage 1 ----
    {
        const __hip_bfloat16* ab[4];
        const __hip_bfloat16* bb[5];
#pragma unroll
        for (int m = 0; m < 4; ++m)
            ab[m] = A + (size_t)(r0 + rh * 64 + m * 16 + frow) * 160 + kq * 8;
#pragma unroll
        for (int n = 0; n < 5; ++n)
            bb[n] = W3T + (size_t)(cq * 80 + n * 16 + frow) * 160 + kq * 8;

        f32x4 acc[4][5];
#pragma unroll
        for (int m = 0; m < 4; ++m)
#pragma unroll
            for (int n = 0; n < 5; ++n) {
                f32x4 z = {0.0f, 0.0f, 0.0f, 0.0f};
                acc[m][n] = z;
            }
#pragma unroll
        for (int t = 0; t < 5; ++t) {
            short8 af[4], bfr[5];
#pragma unroll
            for (int m = 0; m < 4; ++m) af[m] = *(const short8*)(ab[m] + t * 32);
#pragma unroll
            for (int n = 0; n < 5; ++n) bfr[n] = *(const short8*)(bb[n] + t * 32);
#pragma unroll
            for (int m = 0; m < 4; ++m)
#pragma unroll
                for (int n = 0; n < 5; ++n)
                    acc[m][n] = __builtin_amdgcn_mfma_f32_16x16x32_bf16(af[m], bfr[n],
                                                                        acc[m][n], 0, 0, 0);
        }
        // relu+bias -> bf16 -> swizzled LDS
        const int crow_base = rh * 64 + (kq << 2);
        const int ccol_base = cq * 80 + frow;
#pragma unroll
        for (int n = 0; n < 5; ++n) {
            int col = ccol_base + n * 16;
            float bv = b3p[col];
#pragma unroll
            for (int m = 0; m < 4; ++m) {
#pragma unroll
                for (int j = 0; j < 4; ++j) {
                    int row = crow_base + m * 16 + j;
                    float v = fmaxf(acc[m][n][j] + bv, 0.0f);
                    int byte = row * 640 + col * 2;
                    byte ^= (row & 7) << 4;
                    *(unsigned short*)(h3 + byte) = f2bfu(v);
                }
            }
        }
    }
    __syncthreads();
    // ---- stage 2 ----
    {
        const __hip_bfloat16* bb[4];
#pragma unroll
        for (int n = 0; n < 4; ++n)
            bb[n] = WTF + (size_t)(cq * 64 + n * 16 + frow) * 320 + kq * 8;
        int abase[4], aswz[4];
#pragma unroll
        for (int m = 0; m < 4; ++m) {
            int row = rh * 64 + m * 16 + frow;
            abase[m] = row * 640 + kq * 16;
            aswz[m] = (row & 7) << 4;
        }
        f32x4 acc[4][4];
#pragma unroll
        for (int m = 0; m < 4; ++m)
#pragma unroll
            for (int n = 0; n < 4; ++n) {
                f32x4 z = {0.0f, 0.0f, 0.0f, 0.0f};
                acc[m][n] = z;
            }
#pragma unroll
        for (int t = 0; t < 10; ++t) {
            short8 af[4], bfr[4];
#pragma unroll
            for (int m = 0; m < 4; ++m)
                af[m] = *(const short8*)(h3 + ((abase[m] + t * 64) ^ aswz[m]));
#pragma unroll
            for (int n = 0; n < 4; ++n) bfr[n] = *(const short8*)(bb[n] + t * 32);
#pragma unroll
            for (int m = 0; m < 4; ++m)
#pragma unroll
                for (int n = 0; n < 4; ++n)
                    acc[m][n] = __builtin_amdgcn_mfma_f32_16x16x32_bf16(af[m], bfr[n],
                                                                        acc[m][n], 0, 0, 0);
        }
        const int crow0 = r0 + rh * 64 + (kq << 2);
        const int ccol0 = cq * 64 + frow;
#pragma unroll
        for (int n = 0; n < 4; ++n) {
            int col = ccol0 + n * 16;
            if (col >= 200) continue;
            float bv = bFp[col];
#pragma unroll
            for (int m = 0; m < 4; ++m) {
#pragma unroll
                for (int j = 0; j < 4; ++j) {
                    int row = crow0 + m * 16 + j;
                    int drow = rowmap[row];
                    if (drow >= 0) out[(size_t)drow * 200 + col] = acc[m][n][j] + bv;
                }
            }
        }
    }
}

// ---------------- launch ----------------

static inline char* align256(char* p) {
    return (char*)(((uintptr_t)p + 255) & ~(uintptr_t)255);
}

extern "C" void kernel_launch(void* const* d_in, const int* in_sizes, int n_in,
                              void* d_out, int out_size, void* d_ws, size_t ws_size,
                              hipStream_t stream) {
    const int N = N_NODES, E = N_EDGES;
    const float* x = (const float*)d_in[0];
    const int* ei = (const int*)d_in[1];
    const int* src = ei;
    const int* dst = ei + E;
    const int* batch = (const int*)d_in[2];
    const int* pmax = (const int*)d_in[3];
    const float* W1 = (const float*)d_in[4];
    const float* b1 = (const float*)d_in[5];
    const float* W2 = (const float*)d_in[6];
    const float* b2 = (const float*)d_in[7];
    const float* W3 = (const float*)d_in[8];
    const float* b3 = (const float*)d_in[9];
    const float* Wfc = (const float*)d_in[10];
    const float* bfc = (const float*)d_in[11];
    float* out = (float*)d_out;

    char* p = (char*)d_ws;
    float* dinv = (float*)p;          p = align256(p + (size_t)N * 4);
    int* deg = (int*)p;               p = align256(p + (size_t)N * 4);
    int* offs = (int*)p;              p = align256(p + (size_t)(N + 1) * 4);
    int* cursor = (int*)p;            p = align256(p + (size_t)N * 4);
    int* excl = (int*)p;              p = align256(p + (size_t)N * 4);
    int* bsum = (int*)p;              p = align256(p + 128 * 4);
    int* csr_src = (int*)p;           p = align256(p + (size_t)E * 4);
    float* csr_w = (float*)p;         p = align256(p + (size_t)E * 4);
    int* startb = (int*)p;            p = align256(p + (size_t)(N_GRAPHS + 1) * 4);
    int* rowmap = (int*)p;            p = align256(p + (size_t)N * 4);
    __hip_bfloat16* WT1 = (__hip_bfloat16*)p;  p = align256(p + 128 * 96 * 2);
    float* b1p = (float*)p;           p = align256(p + 128 * 4);
    __hip_bfloat16* WT2 = (__hip_bfloat16*)p;  p = align256(p + 256 * 96 * 2);
    float* b2p = (float*)p;           p = align256(p + 256 * 4);
    __hip_bfloat16* WT3 = (__hip_bfloat16*)p;  p = align256(p + 384 * 160 * 2);
    float* b3p = (float*)p;           p = align256(p + 384 * 4);
    __hip_bfloat16* WTF = (__hip_bfloat16*)p;  p = align256(p + 256 * 320 * 2);
    float* bFp = (float*)p;           p = align256(p + 256 * 4);
    __hip_bfloat16* bufAgg = (__hip_bfloat16*)p;  p = align256(p + (size_t)N * 320 * 2);
    __hip_bfloat16* bufH = (__hip_bfloat16*)p;    p = align256(p + (size_t)N * 320 * 2);

    // degree + CSR
    hipMemsetAsync(deg, 0, (size_t)N * 4, stream);
    deg_kernel<<<(E + 255) / 256, 256, 0, stream>>>(dst, deg);
    dinv_kernel<<<(N + 255) / 256, 256, 0, stream>>>(deg, dinv);
    scan1_kernel<<<100, 1024, 0, stream>>>(deg, excl, bsum);
    scan2_kernel<<<1, 128, 0, stream>>>(bsum);
    scan3_kernel<<<(N + 255) / 256, 256, 0, stream>>>(excl, bsum, offs, cursor);
    fill_kernel<<<(E + 255) / 256, 256, 0, stream>>>(src, dst, cursor, csr_src, csr_w, dinv);

    // dense-batch mapping
    start_kernel<<<(N + 255) / 256, 256, 0, stream>>>(batch, startb);
    rowmap_kernel<<<(N + 255) / 256, 256, 0, stream>>>(batch, startb, pmax, rowmap);

    // weight prep
    prep_w_kernel<<<(128 * 96 + 255) / 256, 256, 0, stream>>>(W1, b1, 78, 78, 96, 128, WT1, b1p);
    prep_w_kernel<<<(256 * 96 + 255) / 256, 256, 0, stream>>>(W2, b2, 78, 156, 96, 256, WT2, b2p);
    prep_w_kernel<<<(384 * 160 + 255) / 256, 256, 0, stream>>>(W3, b3, 156, 312, 160, 384, WT3, b3p);
    prep_w_kernel<<<(256 * 320 + 255) / 256, 256, 0, stream>>>(Wfc, bfc, 312, 200, 320, 256, WTF, bFp);

    // Layer 1: agg(x) -> [N,96]; gemm -> h1 [N,96]
    agg_f32_v2<<<(N * 48 + 255) / 256, 256, 0, stream>>>(x, offs, csr_src, csr_w, dinv, bufAgg);
    mfma_gemm_kernel<<<dim3(1, N / 128), 256, 0, stream>>>(
        bufAgg, 96, WT1, b1p, 3, bufH, 96, 96, nullptr, 1);

    // Layer 2: agg -> [N,96]; gemm -> h2 [N,160]
    agg_bf16_v2<96><<<(N * 24 + 255) / 256, 256, 0, stream>>>(bufH, offs, csr_src, csr_w, dinv, bufAgg);
    mfma_gemm_kernel<<<dim3(2, N / 128), 256, 0, stream>>>(
        bufAgg, 96, WT2, b2p, 3, bufH, 160, 160, nullptr, 1);

    // Layer 3 agg -> [N,160]; fused gemm3+FC (h3 never leaves LDS)
    agg_bf16_v2<160><<<(N * 40 + 255) / 256, 256, 0, stream>>>(bufH, offs, csr_src, csr_w, dinv, bufAgg);
    padzero_kernel<<<dim3(25, N_GRAPHS), 256, 0, stream>>>(startb, out);
    gemm3fc_kernel<<<N / 128, 512, 0, stream>>>(bufAgg, WT3, b3p, WTF, bFp, out, rowmap);
}

// Round 7
// 327.368 us; speedup vs baseline: 1.1766x; 1.0338x over previous
//
#include <hip/hip_runtime.h>
#include <hip/hip_bf16.h>
#include <stdint.h>

#define N_NODES 102400
#define N_EDGES 409600
#define N_GRAPHS 2048
#define MAXN 64

typedef __attribute__((ext_vector_type(8))) short short8;
typedef __attribute__((ext_vector_type(4))) float f32x4;

static __device__ __forceinline__ float bfu2f(unsigned short u) {
    union { unsigned int i; float f; } v;
    v.i = ((unsigned int)u) << 16;
    return v.f;
}
static __device__ __forceinline__ unsigned short f2bfu(float f) {
    __hip_bfloat16 h = __float2bfloat16(f);
    return *reinterpret_cast<unsigned short*>(&h);
}

static __device__ __forceinline__ void gload16(const void* g, void* l) {
    __builtin_amdgcn_global_load_lds((const __attribute__((address_space(1))) void*)g,
                                     (__attribute__((address_space(3))) void*)l, 16, 0, 0);
}

// ---------------- degree / CSR build ----------------

__global__ void deg_kernel(const int* __restrict__ dst, int* __restrict__ deg) {
    int e = blockIdx.x * blockDim.x + threadIdx.x;
    if (e < N_EDGES) atomicAdd(&deg[dst[e]], 1);
}

__global__ void dinv_kernel(const int* __restrict__ deg, float* __restrict__ dinv) {
    int i = blockIdx.x * blockDim.x + threadIdx.x;
    if (i < N_NODES) dinv[i] = rsqrtf((float)deg[i] + 1.0f);
}

__global__ void scan1_kernel(const int* __restrict__ deg, int* __restrict__ excl,
                             int* __restrict__ bsum) {
    __shared__ int sh[1024];
    int tid = threadIdx.x;
    int gid = blockIdx.x * 1024 + tid;   // N = 100*1024 exactly
    int v = deg[gid];
    sh[tid] = v;
    __syncthreads();
    for (int off = 1; off < 1024; off <<= 1) {
        int t = (tid >= off) ? sh[tid - off] : 0;
        __syncthreads();
        sh[tid] += t;
        __syncthreads();
    }
    excl[gid] = sh[tid] - v;
    if (tid == 1023) bsum[blockIdx.x] = sh[tid];
}

__global__ void scan2_kernel(int* __restrict__ bsum) {  // 100 entries
    __shared__ int sh[128];
    int tid = threadIdx.x;
    int v = (tid < 100) ? bsum[tid] : 0;
    sh[tid] = v;
    __syncthreads();
    for (int off = 1; off < 128; off <<= 1) {
        int t = (tid >= off) ? sh[tid - off] : 0;
        __syncthreads();
        sh[tid] += t;
        __syncthreads();
    }
    if (tid < 100) bsum[tid] = sh[tid] - v;
}

__global__ void scan3_kernel(const int* __restrict__ excl, const int* __restrict__ bsum,
                             int* __restrict__ offs, int* __restrict__ cursor) {
    int gid = blockIdx.x * blockDim.x + threadIdx.x;
    if (gid < N_NODES) {
        int o = excl[gid] + bsum[gid >> 10];
        offs[gid] = o;
        cursor[gid] = o;
    }
    if (gid == 0) offs[N_NODES] = N_EDGES;
}

__global__ void fill_kernel(const int* __restrict__ src, const int* __restrict__ dst,
                            int* __restrict__ cursor, int* __restrict__ csr_src,
                            float* __restrict__ csr_w, const float* __restrict__ dinv) {
    int e = blockIdx.x * blockDim.x + threadIdx.x;
    if (e >= N_EDGES) return;
    int s = src[e], d = dst[e];
    int pos = atomicAdd(&cursor[d], 1);
    csr_src[pos] = s;
    csr_w[pos] = dinv[s] * dinv[d];
}

// ---------------- to_dense_batch row mapping ----------------

__global__ void start_kernel(const int* __restrict__ batch, int* __restrict__ startb) {
    int i = blockIdx.x * blockDim.x + threadIdx.x;
    if (i >= N_NODES) return;
    if (i == 0 || batch[i] != batch[i - 1]) startb[batch[i]] = i;
    if (i == 0) startb[N_GRAPHS] = N_NODES;
}

__global__ void rowmap_kernel(const int* __restrict__ batch, const int* __restrict__ startb,
                              const int* __restrict__ pmax, int* __restrict__ rowmap) {
    int i = blockIdx.x * blockDim.x + threadIdx.x;
    if (i >= N_NODES) return;
    int b = batch[i];
    int mx = *pmax;
    int pos = i - startb[b];
    rowmap[i] = (pos < mx) ? (b * mx + pos) : -1;
}

// zero only the padding rows of the dense output: rows (b, pos) with pos >= count[b]
__global__ void padzero_kernel(const int* __restrict__ startb, float* __restrict__ out) {
    int b = blockIdx.y;
    int idx = blockIdx.x * blockDim.x + threadIdx.x;  // covers MAXN*100 float2
    int pos = idx / 100;
    int f = idx - pos * 100;
    int count = startb[b + 1] - startb[b];
    if (pos >= count && pos < MAXN) {
        float2 z = {0.0f, 0.0f};
        *(float2*)(out + ((size_t)b * MAXN + pos) * 200 + f * 2) = z;
    }
}

// ---------------- weight prep ----------------

__global__ void prep_w_kernel(const float* __restrict__ W, const float* __restrict__ b,
                              int K, int Nc, int Kp, int Na,
                              __hip_bfloat16* __restrict__ WT, float* __restrict__ bp) {
    int i = blockIdx.x * blockDim.x + threadIdx.x;
    int total = Na * Kp;
    if (i < total) {
        int c = i / Kp, k = i - c * Kp;
        float v = (c < Nc && k < K) ? W[k * Nc + c] : 0.0f;
        WT[i] = __float2bfloat16(v);
    }
    if (i < Na) bp[i] = (i < Nc) ? b[i] : 0.0f;
}

// ---------------- aggregation: thread-per-(node, chunk), 4-way edge unroll ----------

__global__ __launch_bounds__(256) void agg_f32_v2(
    const float* __restrict__ X,
    const int* __restrict__ offs, const int* __restrict__ csr_src,
    const float* __restrict__ csr_w, const float* __restrict__ dinv,
    __hip_bfloat16* __restrict__ out) {
    constexpr int C = 48;
    int idx = blockIdx.x * blockDim.x + threadIdx.x;
    if (idx >= N_NODES * C) return;
    int node = idx / C;
    int c = idx - node * C;
    int col = c * 2;
    float a0 = 0.0f, a1 = 0.0f;
    if (col < 78) {
        float di = dinv[node];
        float sw = di * di;
        const float* Xr = X + (size_t)node * 78 + col;
        float2 h = *(const float2*)Xr;
        a0 = sw * h.x;
        a1 = sw * h.y;
        int e0 = offs[node], e1 = offs[node + 1];
        int j = e0;
        for (; j + 4 <= e1; j += 4) {
            int s0 = csr_src[j], s1 = csr_src[j + 1], s2 = csr_src[j + 2], s3 = csr_src[j + 3];
            float w0 = csr_w[j], w1 = csr_w[j + 1], w2 = csr_w[j + 2], w3 = csr_w[j + 3];
            float2 v0 = *(const float2*)(X + (size_t)s0 * 78 + col);
            float2 v1 = *(const float2*)(X + (size_t)s1 * 78 + col);
            float2 v2 = *(const float2*)(X + (size_t)s2 * 78 + col);
            float2 v3 = *(const float2*)(X + (size_t)s3 * 78 + col);
            a0 += w0 * v0.x + w1 * v1.x + w2 * v2.x + w3 * v3.x;
            a1 += w0 * v0.y + w1 * v1.y + w2 * v2.y + w3 * v3.y;
        }
        for (; j < e1; ++j) {
            int s = csr_src[j];
            float w = csr_w[j];
            float2 v = *(const float2*)(X + (size_t)s * 78 + col);
            a0 += w * v.x;
            a1 += w * v.y;
        }
    }
    __hip_bfloat162 r;
    r.x = __float2bfloat16(a0);
    r.y = __float2bfloat16(a1);
    *(__hip_bfloat162*)(out + (size_t)node * 96 + col) = r;
}

template <int LD>
__global__ __launch_bounds__(256) void agg_bf16_v2(
    const __hip_bfloat16* __restrict__ H,
    const int* __restrict__ offs, const int* __restrict__ csr_src,
    const float* __restrict__ csr_w, const float* __restrict__ dinv,
    __hip_bfloat16* __restrict__ out) {
    constexpr int C = LD / 4;
    int idx = blockIdx.x * blockDim.x + threadIdx.x;
    if (idx >= N_NODES * C) return;
    int node = idx / C;
    int c = idx - node * C;
    const unsigned short* Hu = (const unsigned short*)H;
    size_t rowoff = (size_t)node * LD + c * 4;
    float di = dinv[node];
    float sw = di * di;
    ushort4 h = *(const ushort4*)(Hu + rowoff);
    float a0 = sw * bfu2f(h.x), a1 = sw * bfu2f(h.y), a2 = sw * bfu2f(h.z), a3 = sw * bfu2f(h.w);
    int e0 = offs[node], e1 = offs[node + 1];
    int j = e0;
    for (; j + 4 <= e1; j += 4) {
        int s0 = csr_src[j], s1 = csr_src[j + 1], s2 = csr_src[j + 2], s3 = csr_src[j + 3];
        float w0 = csr_w[j], w1 = csr_w[j + 1], w2 = csr_w[j + 2], w3 = csr_w[j + 3];
        ushort4 v0 = *(const ushort4*)(Hu + (size_t)s0 * LD + c * 4);
        ushort4 v1 = *(const ushort4*)(Hu + (size_t)s1 * LD + c * 4);
        ushort4 v2 = *(const ushort4*)(Hu + (size_t)s2 * LD + c * 4);
        ushort4 v3 = *(const ushort4*)(Hu + (size_t)s3 * LD + c * 4);
        a0 += w0 * bfu2f(v0.x) + w1 * bfu2f(v1.x) + w2 * bfu2f(v2.x) + w3 * bfu2f(v3.x);
        a1 += w0 * bfu2f(v0.y) + w1 * bfu2f(v1.y) + w2 * bfu2f(v2.y) + w3 * bfu2f(v3.y);
        a2 += w0 * bfu2f(v0.z) + w1 * bfu2f(v1.z) + w2 * bfu2f(v2.z) + w3 * bfu2f(v3.z);
        a3 += w0 * bfu2f(v0.w) + w1 * bfu2f(v1.w) + w2 * bfu2f(v2.w) + w3 * bfu2f(v3.w);
    }
    for (; j < e1; ++j) {
        int s = csr_src[j];
        float w = csr_w[j];
        ushort4 v = *(const ushort4*)(Hu + (size_t)s * LD + c * 4);
        a0 += w * bfu2f(v.x);
        a1 += w * bfu2f(v.y);
        a2 += w * bfu2f(v.z);
        a3 += w * bfu2f(v.w);
    }
    ushort4 r;
    r.x = f2bfu(a0);
    r.y = f2bfu(a1);
    r.z = f2bfu(a2);
    r.w = f2bfu(a3);
    *(ushort4*)((unsigned short*)out + rowoff) = r;
}

// ---------------- bf16 MFMA GEMM (R4 structure: global_load_lds, depth-3, counted vmcnt) ----

__global__ __launch_bounds__(256) void mfma_gemm_kernel(
    const __hip_bfloat16* __restrict__ A, int lda,
    const __hip_bfloat16* __restrict__ WT,
    const float* __restrict__ biasp, int nsteps,
    void* __restrict__ Cout, int ldc, int ccols,
    const int* __restrict__ rowmap, int relu) {
    __shared__ __align__(16) char lds[49152];  // 3 x 16KB

    const int tid = threadIdx.x;
    const int lane = tid & 63;
    const int wid = tid >> 6;
    const int wr = wid >> 1, wc = wid & 1;
    const int r0 = blockIdx.y * 128;
    const int c0 = blockIdx.x * 128;

    const bool isB = (wid >= 2);
    const int half = wid & 1;
    const int srow = half * 64 + (lane >> 2);
    const size_t ldabytes = (size_t)lda * 2;
    const char* gbase = isB ? (const char*)(WT + (size_t)(c0 + srow) * lda)
                            : (const char*)(A + (size_t)(r0 + srow) * lda);
    gbase += (lane & 3) << 4;
    char* lbase = lds + (isB ? 8192 : 0) + half * 4096;

#define STAGE(s, b)                                                            \
    do {                                                                       \
        const char* g_ = gbase + (size_t)(s) * 64;                             \
        char* l_ = lbase + (b) * 16384;                                        \
        gload16(g_, l_);                                                       \
        gload16(g_ + 16 * ldabytes, l_ + 1024);                                \
        gload16(g_ + 32 * ldabytes, l_ + 2048);                                \
        gload16(g_ + 48 * ldabytes, l_ + 3072);                                \
    } while (0)

    const int frow = lane & 15;
    const int fsl = (lane >> 4) << 4;
    int aoff[4], boff[4];
#pragma unroll
    for (int m = 0; m < 4; ++m) aoff[m] = (wr * 64 + m * 16 + frow) * 64 + fsl;
#pragma unroll
    for (int n = 0; n < 4; ++n) boff[n] = 8192 + (wc * 64 + n * 16 + frow) * 64 + fsl;

    f32x4 acc[4][4];
#pragma unroll
    for (int m = 0; m < 4; ++m)
#pragma unroll
        for (int n = 0; n < 4; ++n) {
            f32x4 z = {0.0f, 0.0f, 0.0f, 0.0f};
            acc[m][n] = z;
        }

#define COMPUTE(b)                                                                        \
    do {                                                                                  \
        const char* cb_ = lds + (b) * 16384;                                              \
        short8 af[4], bfr[4];                                                             \
        _Pragma("unroll") for (int m = 0; m < 4; ++m) af[m] = *(const short8*)(cb_ + aoff[m]); \
        _Pragma("unroll") for (int n = 0; n < 4; ++n) bfr[n] = *(const short8*)(cb_ + boff[n]); \
        _Pragma("unroll") for (int m = 0; m < 4; ++m)                                     \
            _Pragma("unroll") for (int n = 0; n < 4; ++n)                                 \
                acc[m][n] = __builtin_amdgcn_mfma_f32_16x16x32_bf16(af[m], bfr[n], acc[m][n], 0, 0, 0); \
    } while (0)

    STAGE(0, 0);
    STAGE(1, 1);
    int t = 0;
    for (; t < nsteps - 1; ++t) {
        asm volatile("s_waitcnt vmcnt(4)" ::: "memory");
        __builtin_amdgcn_s_barrier();
        __builtin_amdgcn_sched_barrier(0);
        if (t + 2 < nsteps) STAGE(t + 2, (t + 2) % 3);
        COMPUTE(t % 3);
        __builtin_amdgcn_sched_barrier(0);
    }
    asm volatile("s_waitcnt vmcnt(0)" ::: "memory");
    __builtin_amdgcn_s_barrier();
    __builtin_amdgcn_sched_barrier(0);
    COMPUTE(t % 3);
#undef STAGE
#undef COMPUTE

    const int crow0 = r0 + wr * 64 + ((lane >> 4) << 2);
    const int ccol0 = c0 + wc * 64 + (lane & 15);
#pragma unroll
    for (int n = 0; n < 4; ++n) {
        int col = ccol0 + n * 16;
        if (col >= ccols) continue;
        float bv = biasp[col];
#pragma unroll
        for (int m = 0; m < 4; ++m) {
#pragma unroll
            for (int j = 0; j < 4; ++j) {
                int row = crow0 + m * 16 + j;
                float v = acc[m][n][j] + bv;
                if (relu) v = fmaxf(v, 0.0f);
                if (rowmap) {
                    int drow = rowmap[row];
                    if (drow >= 0) ((float*)Cout)[(size_t)drow * ldc + col] = v;
                } else {
                    ((__hip_bfloat16*)Cout)[(size_t)row * ldc + col] = __float2bfloat16(v);
                }
            }
        }
    }
}

// ---------------- fused layer3-GEMM + FC v2: 64-row blocks, 40KB LDS ----------------
// Block = 64 rows, 256 threads (4 waves), grid N/64 = 1600.
// Stage 1: h3[64][320] = relu(A[64][160] @ W3T^T + b3) -> LDS (bf16, XOR-swizzled).
//   Wave w -> cols w*80..+80 (4x5 frags, K=160).
// Stage 2: out[64][200] = h3 @ WTF^T + bFp, rowmap scatter.
//   Wave w -> cols w*64..+64 (guard col<200), K=320 from LDS.
// Swizzle: byte ^= (row&7)<<4 within each 640B row -> stage-2 ds_read_b128 ~2-way.

__global__ __launch_bounds__(256) void gemm3fc_kernel(
    const __hip_bfloat16* __restrict__ A,     // [N,160] bf16 (agg of h2)
    const __hip_bfloat16* __restrict__ W3T,   // [384,160] bf16
    const float* __restrict__ b3p,            // [384]
    const __hip_bfloat16* __restrict__ WTF,   // [256,320] bf16
    const float* __restrict__ bFp,            // [256]
    float* __restrict__ out,
    const int* __restrict__ rowmap) {
    __shared__ __align__(16) char h3[64 * 640];  // 40 KB
    const int tid = threadIdx.x;
    const int lane = tid & 63;
    const int w = tid >> 6;  // 0..3
    const int r0 = blockIdx.x * 64;
    const int frow = lane & 15;
    const int kq = lane >> 4;  // 0..3

    // ---- stage 1: 64 x 80 per wave ----
    {
        const __hip_bfloat16* ab[4];
        const __hip_bfloat16* bb[5];
#pragma unroll
        for (int m = 0; m < 4; ++m)
            ab[m] = A + (size_t)(r0 + m * 16 + frow) * 160 + kq * 8;
#pragma unroll
        for (int n = 0; n < 5; ++n)
            bb[n] = W3T + (size_t)(w * 80 + n * 16 + frow) * 160 + kq * 8;

        f32x4 acc[4][5];
#pragma unroll
        for (int m = 0; m < 4; ++m)
#pragma unroll
            for (int n = 0; n < 5; ++n) {
                f32x4 z = {0.0f, 0.0f, 0.0f, 0.0f};
                acc[m][n] = z;
            }
#pragma unroll
        for (int t = 0; t < 5; ++t) {
            short8 af[4], bfr[5];
#pragma unroll
            for (int m = 0; m < 4; ++m) af[m] = *(const short8*)(ab[m] + t * 32);
#pragma unroll
            for (int n = 0; n < 5; ++n) bfr[n] = *(const short8*)(bb[n] + t * 32);
#pragma unroll
            for (int m = 0; m < 4; ++m)
#pragma unroll
                for (int n = 0; n < 5; ++n)
                    acc[m][n] = __builtin_amdgcn_mfma_f32_16x16x32_bf16(af[m], bfr[n],
                                                                        acc[m][n], 0, 0, 0);
        }
        // relu+bias -> bf16 -> swizzled LDS
        const int crow_base = kq << 2;
        const int ccol_base = w * 80 + frow;
#pragma unroll
        for (int n = 0; n < 5; ++n) {
            int col = ccol_base + n * 16;
            float bv = b3p[col];
#pragma unroll
            for (int m = 0; m < 4; ++m) {
#pragma unroll
                for (int j = 0; j < 4; ++j) {
                    int row = crow_base + m * 16 + j;
                    float v = fmaxf(acc[m][n][j] + bv, 0.0f);
                    int byte = row * 640 + col * 2;
                    byte ^= (row & 7) << 4;
                    *(unsigned short*)(h3 + byte) = f2bfu(v);
                }
            }
        }
    }
    __syncthreads();
    // ---- stage 2: 64 x 64 per wave (cols w*64, guard <200), K=320 ----
    {
        const __hip_bfloat16* bb[4];
#pragma unroll
        for (int n = 0; n < 4; ++n)
            bb[n] = WTF + (size_t)(w * 64 + n * 16 + frow) * 320 + kq * 8;
        int abase[4], aswz[4];
#pragma unroll
        for (int m = 0; m < 4; ++m) {
            int row = m * 16 + frow;
            abase[m] = row * 640 + kq * 16;
            aswz[m] = (row & 7) << 4;
        }
        f32x4 acc[4][4];
#pragma unroll
        for (int m = 0; m < 4; ++m)
#pragma unroll
            for (int n = 0; n < 4; ++n) {
                f32x4 z = {0.0f, 0.0f, 0.0f, 0.0f};
                acc[m][n] = z;
            }
#pragma unroll
        for (int t = 0; t < 10; ++t) {
            short8 af[4], bfr[4];
#pragma unroll
            for (int m = 0; m < 4; ++m)
                af[m] = *(const short8*)(h3 + ((abase[m] + t * 64) ^ aswz[m]));
#pragma unroll
            for (int n = 0; n < 4; ++n) bfr[n] = *(const short8*)(bb[n] + t * 32);
#pragma unroll
            for (int m = 0; m < 4; ++m)
#pragma unroll
                for (int n = 0; n < 4; ++n)
                    acc[m][n] = __builtin_amdgcn_mfma_f32_16x16x32_bf16(af[m], bfr[n],
                                                                        acc[m][n], 0, 0, 0);
        }
        const int crow0 = r0 + (kq << 2);
        const int ccol0 = w * 64 + frow;
#pragma unroll
        for (int n = 0; n < 4; ++n) {
            int col = ccol0 + n * 16;
            if (col >= 200) continue;
            float bv = bFp[col];
#pragma unroll
            for (int m = 0; m < 4; ++m) {
#pragma unroll
                for (int j = 0; j < 4; ++j) {
                    int row = crow0 + m * 16 + j;
                    int drow = rowmap[row];
                    if (drow >= 0) out[(size_t)drow * 200 + col] = acc[m][n][j] + bv;
                }
            }
        }
    }
}

// ---------------- launch ----------------

static inline char* align256(char* p) {
    return (char*)(((uintptr_t)p + 255) & ~(uintptr_t)255);
}

extern "C" void kernel_launch(void* const* d_in, const int* in_sizes, int n_in,
                              void* d_out, int out_size, void* d_ws, size_t ws_size,
                              hipStream_t stream) {
    const int N = N_NODES, E = N_EDGES;
    const float* x = (const float*)d_in[0];
    const int* ei = (const int*)d_in[1];
    const int* src = ei;
    const int* dst = ei + E;
    const int* batch = (const int*)d_in[2];
    const int* pmax = (const int*)d_in[3];
    const float* W1 = (const float*)d_in[4];
    const float* b1 = (const float*)d_in[5];
    const float* W2 = (const float*)d_in[6];
    const float* b2 = (const float*)d_in[7];
    const float* W3 = (const float*)d_in[8];
    const float* b3 = (const float*)d_in[9];
    const float* Wfc = (const float*)d_in[10];
    const float* bfc = (const float*)d_in[11];
    float* out = (float*)d_out;

    char* p = (char*)d_ws;
    float* dinv = (float*)p;          p = align256(p + (size_t)N * 4);
    int* deg = (int*)p;               p = align256(p + (size_t)N * 4);
    int* offs = (int*)p;              p = align256(p + (size_t)(N + 1) * 4);
    int* cursor = (int*)p;            p = align256(p + (size_t)N * 4);
    int* excl = (int*)p;              p = align256(p + (size_t)N * 4);
    int* bsum = (int*)p;              p = align256(p + 128 * 4);
    int* csr_src = (int*)p;           p = align256(p + (size_t)E * 4);
    float* csr_w = (float*)p;         p = align256(p + (size_t)E * 4);
    int* startb = (int*)p;            p = align256(p + (size_t)(N_GRAPHS + 1) * 4);
    int* rowmap = (int*)p;            p = align256(p + (size_t)N * 4);
    __hip_bfloat16* WT1 = (__hip_bfloat16*)p;  p = align256(p + 128 * 96 * 2);
    float* b1p = (float*)p;           p = align256(p + 128 * 4);
    __hip_bfloat16* WT2 = (__hip_bfloat16*)p;  p = align256(p + 256 * 96 * 2);
    float* b2p = (float*)p;           p = align256(p + 256 * 4);
    __hip_bfloat16* WT3 = (__hip_bfloat16*)p;  p = align256(p + 384 * 160 * 2);
    float* b3p = (float*)p;           p = align256(p + 384 * 4);
    __hip_bfloat16* WTF = (__hip_bfloat16*)p;  p = align256(p + 256 * 320 * 2);
    float* bFp = (float*)p;           p = align256(p + 256 * 4);
    __hip_bfloat16* bufAgg = (__hip_bfloat16*)p;  p = align256(p + (size_t)N * 320 * 2);
    __hip_bfloat16* bufH = (__hip_bfloat16*)p;    p = align256(p + (size_t)N * 320 * 2);

    // degree + CSR
    hipMemsetAsync(deg, 0, (size_t)N * 4, stream);
    deg_kernel<<<(E + 255) / 256, 256, 0, stream>>>(dst, deg);
    dinv_kernel<<<(N + 255) / 256, 256, 0, stream>>>(deg, dinv);
    scan1_kernel<<<100, 1024, 0, stream>>>(deg, excl, bsum);
    scan2_kernel<<<1, 128, 0, stream>>>(bsum);
    scan3_kernel<<<(N + 255) / 256, 256, 0, stream>>>(excl, bsum, offs, cursor);
    fill_kernel<<<(E + 255) / 256, 256, 0, stream>>>(src, dst, cursor, csr_src, csr_w, dinv);

    // dense-batch mapping
    start_kernel<<<(N + 255) / 256, 256, 0, stream>>>(batch, startb);
    rowmap_kernel<<<(N + 255) / 256, 256, 0, stream>>>(batch, startb, pmax, rowmap);

    // weight prep
    prep_w_kernel<<<(128 * 96 + 255) / 256, 256, 0, stream>>>(W1, b1, 78, 78, 96, 128, WT1, b1p);
    prep_w_kernel<<<(256 * 96 + 255) / 256, 256, 0, stream>>>(W2, b2, 78, 156, 96, 256, WT2, b2p);
    prep_w_kernel<<<(384 * 160 + 255) / 256, 256, 0, stream>>>(W3, b3, 156, 312, 160, 384, WT3, b3p);
    prep_w_kernel<<<(256 * 320 + 255) / 256, 256, 0, stream>>>(Wfc, bfc, 312, 200, 320, 256, WTF, bFp);

    // Layer 1: agg(x) -> [N,96]; gemm -> h1 [N,96]
    agg_f32_v2<<<(N * 48 + 255) / 256, 256, 0, stream>>>(x, offs, csr_src, csr_w, dinv, bufAgg);
    mfma_gemm_kernel<<<dim3(1, N / 128), 256, 0, stream>>>(
        bufAgg, 96, WT1, b1p, 3, bufH, 96, 96, nullptr, 1);

    // Layer 2: agg -> [N,96]; gemm -> h2 [N,160]
    agg_bf16_v2<96><<<(N * 24 + 255) / 256, 256, 0, stream>>>(bufH, offs, csr_src, csr_w, dinv, bufAgg);
    mfma_gemm_kernel<<<dim3(2, N / 128), 256, 0, stream>>>(
        bufAgg, 96, WT2, b2p, 3, bufH, 160, 160, nullptr, 1);

    // Layer 3 agg -> [N,160]; fused gemm3+FC (h3 never leaves HBM)
    agg_bf16_v2<160><<<(N * 40 + 255) / 256, 256, 0, stream>>>(bufH, offs, csr_src, csr_w, dinv, bufAgg);
    padzero_kernel<<<dim3(25, N_GRAPHS), 256, 0, stream>>>(startb, out);
    gemm3fc_kernel<<<N / 64, 256, 0, stream>>>(bufAgg, WT3, b3p, WTF, bFp, out, rowmap);
}

// Round 8
// 311.532 us; speedup vs baseline: 1.2364x; 1.0508x over previous
//
#include <hip/hip_runtime.h>
#include <hip/hip_bf16.h>
#include <stdint.h>

#define N_NODES 102400
#define N_EDGES 409600
#define N_GRAPHS 2048
#define MAXN 64

typedef __attribute__((ext_vector_type(8))) short short8;
typedef __attribute__((ext_vector_type(4))) float f32x4;

static __device__ __forceinline__ float bfu2f(unsigned short u) {
    union { unsigned int i; float f; } v;
    v.i = ((unsigned int)u) << 16;
    return v.f;
}
static __device__ __forceinline__ unsigned short f2bfu(float f) {
    __hip_bfloat16 h = __float2bfloat16(f);
    return *reinterpret_cast<unsigned short*>(&h);
}

static __device__ __forceinline__ void gload16(const void* g, void* l) {
    __builtin_amdgcn_global_load_lds((const __attribute__((address_space(1))) void*)g,
                                     (__attribute__((address_space(3))) void*)l, 16, 0, 0);
}

// ---------------- degree / CSR build ----------------

__global__ void deg_kernel(const int* __restrict__ dst, int* __restrict__ deg) {
    int e = blockIdx.x * blockDim.x + threadIdx.x;
    if (e < N_EDGES) atomicAdd(&deg[dst[e]], 1);
}

__global__ void dinv_kernel(const int* __restrict__ deg, float* __restrict__ dinv) {
    int i = blockIdx.x * blockDim.x + threadIdx.x;
    if (i < N_NODES) dinv[i] = rsqrtf((float)deg[i] + 1.0f);
}

__global__ void scan1_kernel(const int* __restrict__ deg, int* __restrict__ excl,
                             int* __restrict__ bsum) {
    __shared__ int sh[1024];
    int tid = threadIdx.x;
    int gid = blockIdx.x * 1024 + tid;   // N = 100*1024 exactly
    int v = deg[gid];
    sh[tid] = v;
    __syncthreads();
    for (int off = 1; off < 1024; off <<= 1) {
        int t = (tid >= off) ? sh[tid - off] : 0;
        __syncthreads();
        sh[tid] += t;
        __syncthreads();
    }
    excl[gid] = sh[tid] - v;
    if (tid == 1023) bsum[blockIdx.x] = sh[tid];
}

__global__ void scan2_kernel(int* __restrict__ bsum) {  // 100 entries
    __shared__ int sh[128];
    int tid = threadIdx.x;
    int v = (tid < 100) ? bsum[tid] : 0;
    sh[tid] = v;
    __syncthreads();
    for (int off = 1; off < 128; off <<= 1) {
        int t = (tid >= off) ? sh[tid - off] : 0;
        __syncthreads();
        sh[tid] += t;
        __syncthreads();
    }
    if (tid < 100) bsum[tid] = sh[tid] - v;
}

__global__ void scan3_kernel(const int* __restrict__ excl, const int* __restrict__ bsum,
                             int* __restrict__ offs, int* __restrict__ cursor) {
    int gid = blockIdx.x * blockDim.x + threadIdx.x;
    if (gid < N_NODES) {
        int o = excl[gid] + bsum[gid >> 10];
        offs[gid] = o;
        cursor[gid] = o;
    }
    if (gid == 0) offs[N_NODES] = N_EDGES;
}

__global__ void fill_kernel(const int* __restrict__ src, const int* __restrict__ dst,
                            int* __restrict__ cursor, int* __restrict__ csr_src,
                            float* __restrict__ csr_w, const float* __restrict__ dinv) {
    int e = blockIdx.x * blockDim.x + threadIdx.x;
    if (e >= N_EDGES) return;
    int s = src[e], d = dst[e];
    int pos = atomicAdd(&cursor[d], 1);
    csr_src[pos] = s;
    csr_w[pos] = dinv[s] * dinv[d];
}

// ---------------- to_dense_batch row mapping ----------------

__global__ void start_kernel(const int* __restrict__ batch, int* __restrict__ startb) {
    int i = blockIdx.x * blockDim.x + threadIdx.x;
    if (i >= N_NODES) return;
    if (i == 0 || batch[i] != batch[i - 1]) startb[batch[i]] = i;
    if (i == 0) startb[N_GRAPHS] = N_NODES;
}

__global__ void rowmap_kernel(const int* __restrict__ batch, const int* __restrict__ startb,
                              const int* __restrict__ pmax, int* __restrict__ rowmap) {
    int i = blockIdx.x * blockDim.x + threadIdx.x;
    if (i >= N_NODES) return;
    int b = batch[i];
    int mx = *pmax;
    int pos = i - startb[b];
    rowmap[i] = (pos < mx) ? (b * mx + pos) : -1;
}

// zero only the padding rows of the dense output: rows (b, pos) with pos >= count[b]
__global__ void padzero_kernel(const int* __restrict__ startb, float* __restrict__ out) {
    int b = blockIdx.y;
    int idx = blockIdx.x * blockDim.x + threadIdx.x;  // covers MAXN*100 float2
    int pos = idx / 100;
    int f = idx - pos * 100;
    int count = startb[b + 1] - startb[b];
    if (pos >= count && pos < MAXN) {
        float2 z = {0.0f, 0.0f};
        *(float2*)(out + ((size_t)b * MAXN + pos) * 200 + f * 2) = z;
    }
}

// ---------------- weight prep ----------------

__global__ void prep_w_kernel(const float* __restrict__ W, const float* __restrict__ b,
                              int K, int Nc, int Kp, int Na,
                              __hip_bfloat16* __restrict__ WT, float* __restrict__ bp) {
    int i = blockIdx.x * blockDim.x + threadIdx.x;
    int total = Na * Kp;
    if (i < total) {
        int c = i / Kp, k = i - c * Kp;
        float v = (c < Nc && k < K) ? W[k * Nc + c] : 0.0f;
        WT[i] = __float2bfloat16(v);
    }
    if (i < Na) bp[i] = (i < Nc) ? b[i] : 0.0f;
}

// ---------------- aggregation: thread-per-(node, chunk), 4-way edge unroll ----------

__global__ __launch_bounds__(256) void agg_f32_v2(
    const float* __restrict__ X,
    const int* __restrict__ offs, const int* __restrict__ csr_src,
    const float* __restrict__ csr_w, const float* __restrict__ dinv,
    __hip_bfloat16* __restrict__ out) {
    constexpr int C = 48;
    int idx = blockIdx.x * blockDim.x + threadIdx.x;
    if (idx >= N_NODES * C) return;
    int node = idx / C;
    int c = idx - node * C;
    int col = c * 2;
    float a0 = 0.0f, a1 = 0.0f;
    if (col < 78) {
        float di = dinv[node];
        float sw = di * di;
        const float* Xr = X + (size_t)node * 78 + col;
        float2 h = *(const float2*)Xr;
        a0 = sw * h.x;
        a1 = sw * h.y;
        int e0 = offs[node], e1 = offs[node + 1];
        int j = e0;
        for (; j + 4 <= e1; j += 4) {
            int s0 = csr_src[j], s1 = csr_src[j + 1], s2 = csr_src[j + 2], s3 = csr_src[j + 3];
            float w0 = csr_w[j], w1 = csr_w[j + 1], w2 = csr_w[j + 2], w3 = csr_w[j + 3];
            float2 v0 = *(const float2*)(X + (size_t)s0 * 78 + col);
            float2 v1 = *(const float2*)(X + (size_t)s1 * 78 + col);
            float2 v2 = *(const float2*)(X + (size_t)s2 * 78 + col);
            float2 v3 = *(const float2*)(X + (size_t)s3 * 78 + col);
            a0 += w0 * v0.x + w1 * v1.x + w2 * v2.x + w3 * v3.x;
            a1 += w0 * v0.y + w1 * v1.y + w2 * v2.y + w3 * v3.y;
        }
        for (; j < e1; ++j) {
            int s = csr_src[j];
            float w = csr_w[j];
            float2 v = *(const float2*)(X + (size_t)s * 78 + col);
            a0 += w * v.x;
            a1 += w * v.y;
        }
    }
    __hip_bfloat162 r;
    r.x = __float2bfloat16(a0);
    r.y = __float2bfloat16(a1);
    *(__hip_bfloat162*)(out + (size_t)node * 96 + col) = r;
}

template <int LD>
__global__ __launch_bounds__(256) void agg_bf16_v2(
    const __hip_bfloat16* __restrict__ H,
    const int* __restrict__ offs, const int* __restrict__ csr_src,
    const float* __restrict__ csr_w, const float* __restrict__ dinv,
    __hip_bfloat16* __restrict__ out) {
    constexpr int C = LD / 4;
    int idx = blockIdx.x * blockDim.x + threadIdx.x;
    if (idx >= N_NODES * C) return;
    int node = idx / C;
    int c = idx - node * C;
    const unsigned short* Hu = (const unsigned short*)H;
    size_t rowoff = (size_t)node * LD + c * 4;
    float di = dinv[node];
    float sw = di * di;
    ushort4 h = *(const ushort4*)(Hu + rowoff);
    float a0 = sw * bfu2f(h.x), a1 = sw * bfu2f(h.y), a2 = sw * bfu2f(h.z), a3 = sw * bfu2f(h.w);
    int e0 = offs[node], e1 = offs[node + 1];
    int j = e0;
    for (; j + 4 <= e1; j += 4) {
        int s0 = csr_src[j], s1 = csr_src[j + 1], s2 = csr_src[j + 2], s3 = csr_src[j + 3];
        float w0 = csr_w[j], w1 = csr_w[j + 1], w2 = csr_w[j + 2], w3 = csr_w[j + 3];
        ushort4 v0 = *(const ushort4*)(Hu + (size_t)s0 * LD + c * 4);
        ushort4 v1 = *(const ushort4*)(Hu + (size_t)s1 * LD + c * 4);
        ushort4 v2 = *(const ushort4*)(Hu + (size_t)s2 * LD + c * 4);
        ushort4 v3 = *(const ushort4*)(Hu + (size_t)s3 * LD + c * 4);
        a0 += w0 * bfu2f(v0.x) + w1 * bfu2f(v1.x) + w2 * bfu2f(v2.x) + w3 * bfu2f(v3.x);
        a1 += w0 * bfu2f(v0.y) + w1 * bfu2f(v1.y) + w2 * bfu2f(v2.y) + w3 * bfu2f(v3.y);
        a2 += w0 * bfu2f(v0.z) + w1 * bfu2f(v1.z) + w2 * bfu2f(v2.z) + w3 * bfu2f(v3.z);
        a3 += w0 * bfu2f(v0.w) + w1 * bfu2f(v1.w) + w2 * bfu2f(v2.w) + w3 * bfu2f(v3.w);
    }
    for (; j < e1; ++j) {
        int s = csr_src[j];
        float w = csr_w[j];
        ushort4 v = *(const ushort4*)(Hu + (size_t)s * LD + c * 4);
        a0 += w * bfu2f(v.x);
        a1 += w * bfu2f(v.y);
        a2 += w * bfu2f(v.z);
        a3 += w * bfu2f(v.w);
    }
    ushort4 r;
    r.x = f2bfu(a0);
    r.y = f2bfu(a1);
    r.z = f2bfu(a2);
    r.w = f2bfu(a3);
    *(ushort4*)((unsigned short*)out + rowoff) = r;
}

// ---------------- bf16 MFMA GEMM (R4 staging; SWAPPED operands -> vector epilogue) ----
// mfma(Wfrag, Afrag): D maps node_row = lane&15 (+m*16), out_col = (lane>>4)*4+j (+n*16).
// Epilogue packs 4 consecutive cols per lane -> ushort4 (bf16) / float4 (fp32) stores.

__global__ __launch_bounds__(256) void mfma_gemm_kernel(
    const __hip_bfloat16* __restrict__ A, int lda,
    const __hip_bfloat16* __restrict__ WT,
    const float* __restrict__ biasp, int nsteps,
    void* __restrict__ Cout, int ldc, int ccols,
    const int* __restrict__ rowmap, int relu) {
    __shared__ __align__(16) char lds[49152];  // 3 x 16KB

    const int tid = threadIdx.x;
    const int lane = tid & 63;
    const int wid = tid >> 6;
    const int wr = wid >> 1, wc = wid & 1;
    const int r0 = blockIdx.y * 128;
    const int c0 = blockIdx.x * 128;

    const bool isB = (wid >= 2);
    const int half = wid & 1;
    const int srow = half * 64 + (lane >> 2);
    const size_t ldabytes = (size_t)lda * 2;
    const char* gbase = isB ? (const char*)(WT + (size_t)(c0 + srow) * lda)
                            : (const char*)(A + (size_t)(r0 + srow) * lda);
    gbase += (lane & 3) << 4;
    char* lbase = lds + (isB ? 8192 : 0) + half * 4096;

#define STAGE(s, b)                                                            \
    do {                                                                       \
        const char* g_ = gbase + (size_t)(s) * 64;                             \
        char* l_ = lbase + (b) * 16384;                                        \
        gload16(g_, l_);                                                       \
        gload16(g_ + 16 * ldabytes, l_ + 1024);                                \
        gload16(g_ + 32 * ldabytes, l_ + 2048);                                \
        gload16(g_ + 48 * ldabytes, l_ + 3072);                                \
    } while (0)

    const int frow = lane & 15;
    const int fsl = (lane >> 4) << 4;
    int aoff[4], boff[4];
#pragma unroll
    for (int m = 0; m < 4; ++m) aoff[m] = (wr * 64 + m * 16 + frow) * 64 + fsl;
#pragma unroll
    for (int n = 0; n < 4; ++n) boff[n] = 8192 + (wc * 64 + n * 16 + frow) * 64 + fsl;

    f32x4 acc[4][4];
#pragma unroll
    for (int m = 0; m < 4; ++m)
#pragma unroll
        for (int n = 0; n < 4; ++n) {
            f32x4 z = {0.0f, 0.0f, 0.0f, 0.0f};
            acc[m][n] = z;
        }

#define COMPUTE(b)                                                                        \
    do {                                                                                  \
        const char* cb_ = lds + (b) * 16384;                                              \
        short8 af[4], bfr[4];                                                             \
        _Pragma("unroll") for (int m = 0; m < 4; ++m) af[m] = *(const short8*)(cb_ + aoff[m]); \
        _Pragma("unroll") for (int n = 0; n < 4; ++n) bfr[n] = *(const short8*)(cb_ + boff[n]); \
        _Pragma("unroll") for (int m = 0; m < 4; ++m)                                     \
            _Pragma("unroll") for (int n = 0; n < 4; ++n)                                 \
                acc[m][n] = __builtin_amdgcn_mfma_f32_16x16x32_bf16(bfr[n], af[m], acc[m][n], 0, 0, 0); \
    } while (0)

    STAGE(0, 0);
    STAGE(1, 1);
    int t = 0;
    for (; t < nsteps - 1; ++t) {
        asm volatile("s_waitcnt vmcnt(4)" ::: "memory");
        __builtin_amdgcn_s_barrier();
        __builtin_amdgcn_sched_barrier(0);
        if (t + 2 < nsteps) STAGE(t + 2, (t + 2) % 3);
        COMPUTE(t % 3);
        __builtin_amdgcn_sched_barrier(0);
    }
    asm volatile("s_waitcnt vmcnt(0)" ::: "memory");
    __builtin_amdgcn_s_barrier();
    __builtin_amdgcn_sched_barrier(0);
    COMPUTE(t % 3);
#undef STAGE
#undef COMPUTE

    // epilogue (swapped): row = r0+wr*64+m*16+(lane&15); col0 = c0+wc*64+n*16+(lane>>4)*4
    const int nrow0 = r0 + wr * 64 + (lane & 15);
    const int ncol0 = c0 + wc * 64 + ((lane >> 4) << 2);
#pragma unroll
    for (int m = 0; m < 4; ++m) {
        int row = nrow0 + m * 16;
        int drow = rowmap ? rowmap[row] : row;
#pragma unroll
        for (int n = 0; n < 4; ++n) {
            int col0 = ncol0 + n * 16;
            if (col0 >= ccols) continue;
            float4 bv = *(const float4*)(biasp + col0);
            float v0 = acc[m][n][0] + bv.x;
            float v1 = acc[m][n][1] + bv.y;
            float v2 = acc[m][n][2] + bv.z;
            float v3 = acc[m][n][3] + bv.w;
            if (relu) {
                v0 = fmaxf(v0, 0.0f); v1 = fmaxf(v1, 0.0f);
                v2 = fmaxf(v2, 0.0f); v3 = fmaxf(v3, 0.0f);
            }
            if (rowmap) {
                if (drow >= 0) {
                    float4 o = {v0, v1, v2, v3};
                    *(float4*)((float*)Cout + (size_t)drow * ldc + col0) = o;
                }
            } else {
                ushort4 o;
                o.x = f2bfu(v0); o.y = f2bfu(v1); o.z = f2bfu(v2); o.w = f2bfu(v3);
                *(ushort4*)((__hip_bfloat16*)Cout + (size_t)row * ldc + col0) = o;
            }
        }
    }
}

// ---------------- fused layer3-GEMM + FC (swapped operands, vector spill/stores) ------
// Block = 64 rows, 256 threads (4 waves), grid N/64 = 1600.
// Stage 1: h3[64][320] = relu(A[64][160] @ W3T^T + b3) -> LDS bf16, XOR-swizzled,
//   written as ds_write_b64 (4 consecutive cols per lane).
// Stage 2: out[64][200] = h3 @ WTF^T + bFp -> float4 stores via rowmap.
// Swizzle: byte ^= (row&7)<<4 within each 640B row.

__global__ __launch_bounds__(256) void gemm3fc_kernel(
    const __hip_bfloat16* __restrict__ A,     // [N,160] bf16 (agg of h2)
    const __hip_bfloat16* __restrict__ W3T,   // [384,160] bf16
    const float* __restrict__ b3p,            // [384]
    const __hip_bfloat16* __restrict__ WTF,   // [256,320] bf16
    const float* __restrict__ bFp,            // [256]
    float* __restrict__ out,
    const int* __restrict__ rowmap) {
    __shared__ __align__(16) char h3[64 * 640];  // 40 KB
    const int tid = threadIdx.x;
    const int lane = tid & 63;
    const int w = tid >> 6;  // 0..3
    const int r0 = blockIdx.x * 64;
    const int frow = lane & 15;
    const int kq = lane >> 4;  // 0..3

    // ---- stage 1: 64 x 80 per wave ----
    {
        const __hip_bfloat16* ab[4];
        const __hip_bfloat16* bb[5];
#pragma unroll
        for (int m = 0; m < 4; ++m)
            ab[m] = A + (size_t)(r0 + m * 16 + frow) * 160 + kq * 8;
#pragma unroll
        for (int n = 0; n < 5; ++n)
            bb[n] = W3T + (size_t)(w * 80 + n * 16 + frow) * 160 + kq * 8;

        f32x4 acc[4][5];
#pragma unroll
        for (int m = 0; m < 4; ++m)
#pragma unroll
            for (int n = 0; n < 5; ++n) {
                f32x4 z = {0.0f, 0.0f, 0.0f, 0.0f};
                acc[m][n] = z;
            }
#pragma unroll
        for (int t = 0; t < 5; ++t) {
            short8 af[4], bfr[5];
#pragma unroll
            for (int m = 0; m < 4; ++m) af[m] = *(const short8*)(ab[m] + t * 32);
#pragma unroll
            for (int n = 0; n < 5; ++n) bfr[n] = *(const short8*)(bb[n] + t * 32);
#pragma unroll
            for (int m = 0; m < 4; ++m)
#pragma unroll
                for (int n = 0; n < 5; ++n)
                    acc[m][n] = __builtin_amdgcn_mfma_f32_16x16x32_bf16(bfr[n], af[m],
                                                                        acc[m][n], 0, 0, 0);
        }
        // relu+bias -> bf16x4 -> swizzled LDS (ds_write_b64)
#pragma unroll
        for (int m = 0; m < 4; ++m) {
            int row = m * 16 + frow;
            int swz = (row & 7) << 4;
#pragma unroll
            for (int n = 0; n < 5; ++n) {
                int col0 = w * 80 + n * 16 + (kq << 2);
                float4 bv = *(const float4*)(b3p + col0);
                ushort4 o;
                o.x = f2bfu(fmaxf(acc[m][n][0] + bv.x, 0.0f));
                o.y = f2bfu(fmaxf(acc[m][n][1] + bv.y, 0.0f));
                o.z = f2bfu(fmaxf(acc[m][n][2] + bv.z, 0.0f));
                o.w = f2bfu(fmaxf(acc[m][n][3] + bv.w, 0.0f));
                int byte = row * 640 + col0 * 2;
                *(ushort4*)(h3 + (byte ^ swz)) = o;
            }
        }
    }
    __syncthreads();
    // ---- stage 2: 64 x 64 per wave (cols w*64, guard <200), K=320 ----
    {
        const __hip_bfloat16* bb[4];
#pragma unroll
        for (int n = 0; n < 4; ++n)
            bb[n] = WTF + (size_t)(w * 64 + n * 16 + frow) * 320 + kq * 8;
        int abase[4], aswz[4];
#pragma unroll
        for (int m = 0; m < 4; ++m) {
            int row = m * 16 + frow;
            abase[m] = row * 640 + kq * 16;
            aswz[m] = (row & 7) << 4;
        }
        f32x4 acc[4][4];
#pragma unroll
        for (int m = 0; m < 4; ++m)
#pragma unroll
            for (int n = 0; n < 4; ++n) {
                f32x4 z = {0.0f, 0.0f, 0.0f, 0.0f};
                acc[m][n] = z;
            }
#pragma unroll
        for (int t = 0; t < 10; ++t) {
            short8 af[4], bfr[4];
#pragma unroll
            for (int m = 0; m < 4; ++m)
                af[m] = *(const short8*)(h3 + ((abase[m] + t * 64) ^ aswz[m]));
#pragma unroll
            for (int n = 0; n < 4; ++n) bfr[n] = *(const short8*)(bb[n] + t * 32);
#pragma unroll
            for (int m = 0; m < 4; ++m)
#pragma unroll
                for (int n = 0; n < 4; ++n)
                    acc[m][n] = __builtin_amdgcn_mfma_f32_16x16x32_bf16(bfr[n], af[m],
                                                                        acc[m][n], 0, 0, 0);
        }
        // epilogue: row = r0+m*16+(lane&15); col0 = w*64+n*16+kq*4; float4 stores
#pragma unroll
        for (int m = 0; m < 4; ++m) {
            int row = r0 + m * 16 + frow;
            int drow = rowmap[row];
            if (drow < 0) continue;
#pragma unroll
            for (int n = 0; n < 4; ++n) {
                int col0 = w * 64 + n * 16 + (kq << 2);
                if (col0 >= 200) continue;
                float4 bv = *(const float4*)(bFp + col0);
                float4 o;
                o.x = acc[m][n][0] + bv.x;
                o.y = acc[m][n][1] + bv.y;
                o.z = acc[m][n][2] + bv.z;
                o.w = acc[m][n][3] + bv.w;
                *(float4*)(out + (size_t)drow * 200 + col0) = o;
            }
        }
    }
}

// ---------------- launch ----------------

static inline char* align256(char* p) {
    return (char*)(((uintptr_t)p + 255) & ~(uintptr_t)255);
}

extern "C" void kernel_launch(void* const* d_in, const int* in_sizes, int n_in,
                              void* d_out, int out_size, void* d_ws, size_t ws_size,
                              hipStream_t stream) {
    const int N = N_NODES, E = N_EDGES;
    const float* x = (const float*)d_in[0];
    const int* ei = (const int*)d_in[1];
    const int* src = ei;
    const int* dst = ei + E;
    const int* batch = (const int*)d_in[2];
    const int* pmax = (const int*)d_in[3];
    const float* W1 = (const float*)d_in[4];
    const float* b1 = (const float*)d_in[5];
    const float* W2 = (const float*)d_in[6];
    const float* b2 = (const float*)d_in[7];
    const float* W3 = (const float*)d_in[8];
    const float* b3 = (const float*)d_in[9];
    const float* Wfc = (const float*)d_in[10];
    const float* bfc = (const float*)d_in[11];
    float* out = (float*)d_out;

    char* p = (char*)d_ws;
    float* dinv = (float*)p;          p = align256(p + (size_t)N * 4);
    int* deg = (int*)p;               p = align256(p + (size_t)N * 4);
    int* offs = (int*)p;              p = align256(p + (size_t)(N + 1) * 4);
    int* cursor = (int*)p;            p = align256(p + (size_t)N * 4);
    int* excl = (int*)p;              p = align256(p + (size_t)N * 4);
    int* bsum = (int*)p;              p = align256(p + 128 * 4);
    int* csr_src = (int*)p;           p = align256(p + (size_t)E * 4);
    float* csr_w = (float*)p;         p = align256(p + (size_t)E * 4);
    int* startb = (int*)p;            p = align256(p + (size_t)(N_GRAPHS + 1) * 4);
    int* rowmap = (int*)p;            p = align256(p + (size_t)N * 4);
    __hip_bfloat16* WT1 = (__hip_bfloat16*)p;  p = align256(p + 128 * 96 * 2);
    float* b1p = (float*)p;           p = align256(p + 128 * 4);
    __hip_bfloat16* WT2 = (__hip_bfloat16*)p;  p = align256(p + 256 * 96 * 2);
    float* b2p = (float*)p;           p = align256(p + 256 * 4);
    __hip_bfloat16* WT3 = (__hip_bfloat16*)p;  p = align256(p + 384 * 160 * 2);
    float* b3p = (float*)p;           p = align256(p + 384 * 4);
    __hip_bfloat16* WTF = (__hip_bfloat16*)p;  p = align256(p + 256 * 320 * 2);
    float* bFp = (float*)p;           p = align256(p + 256 * 4);
    __hip_bfloat16* bufAgg = (__hip_bfloat16*)p;  p = align256(p + (size_t)N * 320 * 2);
    __hip_bfloat16* bufH = (__hip_bfloat16*)p;    p = align256(p + (size_t)N * 320 * 2);

    // degree + CSR
    hipMemsetAsync(deg, 0, (size_t)N * 4, stream);
    deg_kernel<<<(E + 255) / 256, 256, 0, stream>>>(dst, deg);
    dinv_kernel<<<(N + 255) / 256, 256, 0, stream>>>(deg, dinv);
    scan1_kernel<<<100, 1024, 0, stream>>>(deg, excl, bsum);
    scan2_kernel<<<1, 128, 0, stream>>>(bsum);
    scan3_kernel<<<(N + 255) / 256, 256, 0, stream>>>(excl, bsum, offs, cursor);
    fill_kernel<<<(E + 255) / 256, 256, 0, stream>>>(src, dst, cursor, csr_src, csr_w, dinv);

    // dense-batch mapping
    start_kernel<<<(N + 255) / 256, 256, 0, stream>>>(batch, startb);
    rowmap_kernel<<<(N + 255) / 256, 256, 0, stream>>>(batch, startb, pmax, rowmap);

    // weight prep
    prep_w_kernel<<<(128 * 96 + 255) / 256, 256, 0, stream>>>(W1, b1, 78, 78, 96, 128, WT1, b1p);
    prep_w_kernel<<<(256 * 96 + 255) / 256, 256, 0, stream>>>(W2, b2, 78, 156, 96, 256, WT2, b2p);
    prep_w_kernel<<<(384 * 160 + 255) / 256, 256, 0, stream>>>(W3, b3, 156, 312, 160, 384, WT3, b3p);
    prep_w_kernel<<<(256 * 320 + 255) / 256, 256, 0, stream>>>(Wfc, bfc, 312, 200, 320, 256, WTF, bFp);

    // Layer 1: agg(x) -> [N,96]; gemm -> h1 [N,96]
    agg_f32_v2<<<(N * 48 + 255) / 256, 256, 0, stream>>>(x, offs, csr_src, csr_w, dinv, bufAgg);
    mfma_gemm_kernel<<<dim3(1, N / 128), 256, 0, stream>>>(
        bufAgg, 96, WT1, b1p, 3, bufH, 96, 96, nullptr, 1);

    // Layer 2: agg -> [N,96]; gemm -> h2 [N,160]
    agg_bf16_v2<96><<<(N * 24 + 255) / 256, 256, 0, stream>>>(bufH, offs, csr_src, csr_w, dinv, bufAgg);
    mfma_gemm_kernel<<<dim3(2, N / 128), 256, 0, stream>>>(
        bufAgg, 96, WT2, b2p, 3, bufH, 160, 160, nullptr, 1);

    // Layer 3 agg -> [N,160]; fused gemm3+FC (h3 never touches HBM)
    agg_bf16_v2<160><<<(N * 40 + 255) / 256, 256, 0, stream>>>(bufH, offs, csr_src, csr_w, dinv, bufAgg);
    padzero_kernel<<<dim3(25, N_GRAPHS), 256, 0, stream>>>(startb, out);
    gemm3fc_kernel<<<N / 64, 256, 0, stream>>>(bufAgg, WT3, b3p, WTF, bFp, out, rowmap);
}

// Round 9
// 288.266 us; speedup vs baseline: 1.3362x; 1.0807x over previous
//
#include <hip/hip_runtime.h>
#include <hip/hip_bf16.h>
#include <stdint.h>

#define N_NODES 102400
#define N_EDGES 409600
#define N_GRAPHS 2048
#define MAXN 64

typedef __attribute__((ext_vector_type(8))) short short8;
typedef __attribute__((ext_vector_type(4))) float f32x4;

static __device__ __forceinline__ float bfu2f(unsigned short u) {
    union { unsigned int i; float f; } v;
    v.i = ((unsigned int)u) << 16;
    return v.f;
}
static __device__ __forceinline__ unsigned short f2bfu(float f) {
    __hip_bfloat16 h = __float2bfloat16(f);
    return *reinterpret_cast<unsigned short*>(&h);
}

static __device__ __forceinline__ void gload16(const void* g, void* l) {
    __builtin_amdgcn_global_load_lds((const __attribute__((address_space(1))) void*)g,
                                     (__attribute__((address_space(3))) void*)l, 16, 0, 0);
}

// ---------------- degree / CSR build ----------------

__global__ void deg_kernel(const int* __restrict__ dst, int* __restrict__ deg) {
    int e = blockIdx.x * blockDim.x + threadIdx.x;
    if (e < N_EDGES) atomicAdd(&deg[dst[e]], 1);
}

__global__ void dinv_kernel(const int* __restrict__ deg, float* __restrict__ dinv) {
    int i = blockIdx.x * blockDim.x + threadIdx.x;
    if (i < N_NODES) dinv[i] = rsqrtf((float)deg[i] + 1.0f);
}

__global__ void scan1_kernel(const int* __restrict__ deg, int* __restrict__ excl,
                             int* __restrict__ bsum) {
    __shared__ int sh[1024];
    int tid = threadIdx.x;
    int gid = blockIdx.x * 1024 + tid;   // N = 100*1024 exactly
    int v = deg[gid];
    sh[tid] = v;
    __syncthreads();
    for (int off = 1; off < 1024; off <<= 1) {
        int t = (tid >= off) ? sh[tid - off] : 0;
        __syncthreads();
        sh[tid] += t;
        __syncthreads();
    }
    excl[gid] = sh[tid] - v;
    if (tid == 1023) bsum[blockIdx.x] = sh[tid];
}

__global__ void scan2_kernel(int* __restrict__ bsum) {  // 100 entries
    __shared__ int sh[128];
    int tid = threadIdx.x;
    int v = (tid < 100) ? bsum[tid] : 0;
    sh[tid] = v;
    __syncthreads();
    for (int off = 1; off < 128; off <<= 1) {
        int t = (tid >= off) ? sh[tid - off] : 0;
        __syncthreads();
        sh[tid] += t;
        __syncthreads();
    }
    if (tid < 100) bsum[tid] = sh[tid] - v;
}

__global__ void scan3_kernel(const int* __restrict__ excl, const int* __restrict__ bsum,
                             int* __restrict__ offs, int* __restrict__ cursor) {
    int gid = blockIdx.x * blockDim.x + threadIdx.x;
    if (gid < N_NODES) {
        int o = excl[gid] + bsum[gid >> 10];
        offs[gid] = o;
        cursor[gid] = o;
    }
    if (gid == 0) offs[N_NODES] = N_EDGES;
}

__global__ void fill_kernel(const int* __restrict__ src, const int* __restrict__ dst,
                            int* __restrict__ cursor, int* __restrict__ csr_src,
                            float* __restrict__ csr_w, const float* __restrict__ dinv) {
    int e = blockIdx.x * blockDim.x + threadIdx.x;
    if (e >= N_EDGES) return;
    int s = src[e], d = dst[e];
    int pos = atomicAdd(&cursor[d], 1);
    csr_src[pos] = s;
    csr_w[pos] = dinv[s] * dinv[d];
}

// ---------------- to_dense_batch row mapping ----------------

__global__ void start_kernel(const int* __restrict__ batch, int* __restrict__ startb) {
    int i = blockIdx.x * blockDim.x + threadIdx.x;
    if (i >= N_NODES) return;
    if (i == 0 || batch[i] != batch[i - 1]) startb[batch[i]] = i;
    if (i == 0) startb[N_GRAPHS] = N_NODES;
}

__global__ void rowmap_kernel(const int* __restrict__ batch, const int* __restrict__ startb,
                              const int* __restrict__ pmax, int* __restrict__ rowmap) {
    int i = blockIdx.x * blockDim.x + threadIdx.x;
    if (i >= N_NODES) return;
    int b = batch[i];
    int mx = *pmax;
    int pos = i - startb[b];
    rowmap[i] = (pos < mx) ? (b * mx + pos) : -1;
}

// zero only the padding rows of the dense output: rows (b, pos) with pos >= count[b]
__global__ void padzero_kernel(const int* __restrict__ startb, float* __restrict__ out) {
    int b = blockIdx.y;
    int idx = blockIdx.x * blockDim.x + threadIdx.x;  // covers MAXN*100 float2
    int pos = idx / 100;
    int f = idx - pos * 100;
    int count = startb[b + 1] - startb[b];
    if (pos >= count && pos < MAXN) {
        float2 z = {0.0f, 0.0f};
        *(float2*)(out + ((size_t)b * MAXN + pos) * 200 + f * 2) = z;
    }
}

// ---------------- weight prep ----------------

__global__ void prep_w_kernel(const float* __restrict__ W, const float* __restrict__ b,
                              int K, int Nc, int Kp, int Na,
                              __hip_bfloat16* __restrict__ WT, float* __restrict__ bp) {
    int i = blockIdx.x * blockDim.x + threadIdx.x;
    int total = Na * Kp;
    if (i < total) {
        int c = i / Kp, k = i - c * Kp;
        float v = (c < Nc && k < K) ? W[k * Nc + c] : 0.0f;
        WT[i] = __float2bfloat16(v);
    }
    if (i < Na) bp[i] = (i < Nc) ? b[i] : 0.0f;
}

// ---------------- aggregation v3: thread-per-(node, 16B chunk), 4-way edge unroll ----

// Layer 1: X fp32 [N,78] -> out bf16 [N,96]. C=24 chunks of 4 cols.
// Tail cols (>=78) accumulate garbage from a safe in-bounds offset, zeroed pre-store.
__global__ __launch_bounds__(256) void agg_f32_v3(
    const float* __restrict__ X,
    const int* __restrict__ offs, const int* __restrict__ csr_src,
    const float* __restrict__ csr_w, const float* __restrict__ dinv,
    __hip_bfloat16* __restrict__ out) {
    constexpr int C = 24;
    int idx = blockIdx.x * blockDim.x + threadIdx.x;
    if (idx >= N_NODES * C) return;
    int node = idx / C;
    int c = idx - node * C;
    int col = c * 4;
    float a0 = 0.0f, a1 = 0.0f, a2 = 0.0f, a3 = 0.0f;
    if (col < 78) {
        int colB = (col + 2 < 78) ? col + 2 : 74;  // safe in-bounds; garbage masked later
        float di = dinv[node];
        float sw = di * di;
        const float* Xr = X + (size_t)node * 78;
        float2 s01 = *(const float2*)(Xr + col);
        float2 s23 = *(const float2*)(Xr + colB);
        a0 = sw * s01.x; a1 = sw * s01.y; a2 = sw * s23.x; a3 = sw * s23.y;
        int e0 = offs[node], e1 = offs[node + 1];
        int j = e0;
        for (; j + 4 <= e1; j += 4) {
            int s0 = csr_src[j], s1 = csr_src[j + 1], s2 = csr_src[j + 2], s3 = csr_src[j + 3];
            float w0 = csr_w[j], w1 = csr_w[j + 1], w2 = csr_w[j + 2], w3 = csr_w[j + 3];
            const float* P0 = X + (size_t)s0 * 78;
            const float* P1 = X + (size_t)s1 * 78;
            const float* P2 = X + (size_t)s2 * 78;
            const float* P3 = X + (size_t)s3 * 78;
            float2 u0 = *(const float2*)(P0 + col), v0 = *(const float2*)(P0 + colB);
            float2 u1 = *(const float2*)(P1 + col), v1 = *(const float2*)(P1 + colB);
            float2 u2 = *(const float2*)(P2 + col), v2 = *(const float2*)(P2 + colB);
            float2 u3 = *(const float2*)(P3 + col), v3 = *(const float2*)(P3 + colB);
            a0 += w0 * u0.x + w1 * u1.x + w2 * u2.x + w3 * u3.x;
            a1 += w0 * u0.y + w1 * u1.y + w2 * u2.y + w3 * u3.y;
            a2 += w0 * v0.x + w1 * v1.x + w2 * v2.x + w3 * v3.x;
            a3 += w0 * v0.y + w1 * v1.y + w2 * v2.y + w3 * v3.y;
        }
        for (; j < e1; ++j) {
            int s = csr_src[j];
            float w = csr_w[j];
            const float* P = X + (size_t)s * 78;
            float2 u = *(const float2*)(P + col);
            float2 v = *(const float2*)(P + colB);
            a0 += w * u.x; a1 += w * u.y; a2 += w * v.x; a3 += w * v.y;
        }
        if (col + 2 >= 78) { a2 = 0.0f; a3 = 0.0f; }
    }
    ushort4 r;
    r.x = f2bfu(a0); r.y = f2bfu(a1); r.z = f2bfu(a2); r.w = f2bfu(a3);
    *(ushort4*)((unsigned short*)out + (size_t)node * 96 + col) = r;
}

// Layers 2/3: H bf16 [N,LD] -> out bf16 [N,LD]. C=LD/8 chunks of 8 cols (16B).
template <int LD>
__global__ __launch_bounds__(256) void agg_bf16_v3(
    const __hip_bfloat16* __restrict__ H,
    const int* __restrict__ offs, const int* __restrict__ csr_src,
    const float* __restrict__ csr_w, const float* __restrict__ dinv,
    __hip_bfloat16* __restrict__ out) {
    constexpr int C = LD / 8;
    int idx = blockIdx.x * blockDim.x + threadIdx.x;
    if (idx >= N_NODES * C) return;
    int node = idx / C;
    int c = idx - node * C;
    const unsigned short* Hu = (const unsigned short*)H;
    size_t rowoff = (size_t)node * LD + c * 8;
    float di = dinv[node];
    float sw = di * di;
    short8 h = *(const short8*)(Hu + rowoff);
    float a[8];
#pragma unroll
    for (int i = 0; i < 8; ++i) a[i] = sw * bfu2f((unsigned short)h[i]);
    int e0 = offs[node], e1 = offs[node + 1];
    int j = e0;
    for (; j + 4 <= e1; j += 4) {
        int s0 = csr_src[j], s1 = csr_src[j + 1], s2 = csr_src[j + 2], s3 = csr_src[j + 3];
        float w0 = csr_w[j], w1 = csr_w[j + 1], w2 = csr_w[j + 2], w3 = csr_w[j + 3];
        short8 v0 = *(const short8*)(Hu + (size_t)s0 * LD + c * 8);
        short8 v1 = *(const short8*)(Hu + (size_t)s1 * LD + c * 8);
        short8 v2 = *(const short8*)(Hu + (size_t)s2 * LD + c * 8);
        short8 v3 = *(const short8*)(Hu + (size_t)s3 * LD + c * 8);
#pragma unroll
        for (int i = 0; i < 8; ++i)
            a[i] += w0 * bfu2f((unsigned short)v0[i]) + w1 * bfu2f((unsigned short)v1[i]) +
                    w2 * bfu2f((unsigned short)v2[i]) + w3 * bfu2f((unsigned short)v3[i]);
    }
    for (; j < e1; ++j) {
        int s = csr_src[j];
        float w = csr_w[j];
        short8 v = *(const short8*)(Hu + (size_t)s * LD + c * 8);
#pragma unroll
        for (int i = 0; i < 8; ++i) a[i] += w * bfu2f((unsigned short)v[i]);
    }
    short8 r;
#pragma unroll
    for (int i = 0; i < 8; ++i) r[i] = (short)f2bfu(a[i]);
    *(short8*)((unsigned short*)out + rowoff) = r;
}

// ---------------- bf16 MFMA GEMM (R4 staging; swapped operands -> vector epilogue) ----

__global__ __launch_bounds__(256) void mfma_gemm_kernel(
    const __hip_bfloat16* __restrict__ A, int lda,
    const __hip_bfloat16* __restrict__ WT,
    const float* __restrict__ biasp, int nsteps,
    void* __restrict__ Cout, int ldc, int ccols,
    const int* __restrict__ rowmap, int relu) {
    __shared__ __align__(16) char lds[49152];  // 3 x 16KB

    const int tid = threadIdx.x;
    const int lane = tid & 63;
    const int wid = tid >> 6;
    const int wr = wid >> 1, wc = wid & 1;
    const int r0 = blockIdx.y * 128;
    const int c0 = blockIdx.x * 128;

    const bool isB = (wid >= 2);
    const int half = wid & 1;
    const int srow = half * 64 + (lane >> 2);
    const size_t ldabytes = (size_t)lda * 2;
    const char* gbase = isB ? (const char*)(WT + (size_t)(c0 + srow) * lda)
                            : (const char*)(A + (size_t)(r0 + srow) * lda);
    gbase += (lane & 3) << 4;
    char* lbase = lds + (isB ? 8192 : 0) + half * 4096;

#define STAGE(s, b)                                                            \
    do {                                                                       \
        const char* g_ = gbase + (size_t)(s) * 64;                             \
        char* l_ = lbase + (b) * 16384;                                        \
        gload16(g_, l_);                                                       \
        gload16(g_ + 16 * ldabytes, l_ + 1024);                                \
        gload16(g_ + 32 * ldabytes, l_ + 2048);                                \
        gload16(g_ + 48 * ldabytes, l_ + 3072);                                \
    } while (0)

    const int frow = lane & 15;
    const int fsl = (lane >> 4) << 4;
    int aoff[4], boff[4];
#pragma unroll
    for (int m = 0; m < 4; ++m) aoff[m] = (wr * 64 + m * 16 + frow) * 64 + fsl;
#pragma unroll
    for (int n = 0; n < 4; ++n) boff[n] = 8192 + (wc * 64 + n * 16 + frow) * 64 + fsl;

    f32x4 acc[4][4];
#pragma unroll
    for (int m = 0; m < 4; ++m)
#pragma unroll
        for (int n = 0; n < 4; ++n) {
            f32x4 z = {0.0f, 0.0f, 0.0f, 0.0f};
            acc[m][n] = z;
        }

#define COMPUTE(b)                                                                        \
    do {                                                                                  \
        const char* cb_ = lds + (b) * 16384;                                              \
        short8 af[4], bfr[4];                                                             \
        _Pragma("unroll") for (int m = 0; m < 4; ++m) af[m] = *(const short8*)(cb_ + aoff[m]); \
        _Pragma("unroll") for (int n = 0; n < 4; ++n) bfr[n] = *(const short8*)(cb_ + boff[n]); \
        _Pragma("unroll") for (int m = 0; m < 4; ++m)                                     \
            _Pragma("unroll") for (int n = 0; n < 4; ++n)                                 \
                acc[m][n] = __builtin_amdgcn_mfma_f32_16x16x32_bf16(bfr[n], af[m], acc[m][n], 0, 0, 0); \
    } while (0)

    STAGE(0, 0);
    STAGE(1, 1);
    int t = 0;
    for (; t < nsteps - 1; ++t) {
        asm volatile("s_waitcnt vmcnt(4)" ::: "memory");
        __builtin_amdgcn_s_barrier();
        __builtin_amdgcn_sched_barrier(0);
        if (t + 2 < nsteps) STAGE(t + 2, (t + 2) % 3);
        COMPUTE(t % 3);
        __builtin_amdgcn_sched_barrier(0);
    }
    asm volatile("s_waitcnt vmcnt(0)" ::: "memory");
    __builtin_amdgcn_s_barrier();
    __builtin_amdgcn_sched_barrier(0);
    COMPUTE(t % 3);
#undef STAGE
#undef COMPUTE

    // epilogue (swapped): row = r0+wr*64+m*16+(lane&15); col0 = c0+wc*64+n*16+(lane>>4)*4
    const int nrow0 = r0 + wr * 64 + (lane & 15);
    const int ncol0 = c0 + wc * 64 + ((lane >> 4) << 2);
#pragma unroll
    for (int m = 0; m < 4; ++m) {
        int row = nrow0 + m * 16;
        int drow = rowmap ? rowmap[row] : row;
#pragma unroll
        for (int n = 0; n < 4; ++n) {
            int col0 = ncol0 + n * 16;
            if (col0 >= ccols) continue;
            float4 bv = *(const float4*)(biasp + col0);
            float v0 = acc[m][n][0] + bv.x;
            float v1 = acc[m][n][1] + bv.y;
            float v2 = acc[m][n][2] + bv.z;
            float v3 = acc[m][n][3] + bv.w;
            if (relu) {
                v0 = fmaxf(v0, 0.0f); v1 = fmaxf(v1, 0.0f);
                v2 = fmaxf(v2, 0.0f); v3 = fmaxf(v3, 0.0f);
            }
            if (rowmap) {
                if (drow >= 0) {
                    float4 o = {v0, v1, v2, v3};
                    *(float4*)((float*)Cout + (size_t)drow * ldc + col0) = o;
                }
            } else {
                ushort4 o;
                o.x = f2bfu(v0); o.y = f2bfu(v1); o.z = f2bfu(v2); o.w = f2bfu(v3);
                *(ushort4*)((__hip_bfloat16*)Cout + (size_t)row * ldc + col0) = o;
            }
        }
    }
}

// ---------------- fused layer3-GEMM + FC (vector spill/stores + stage-2 B prefetch) ----
// Block = 64 rows, 256 threads (4 waves), grid N/64 = 1600.
// Stage 1: h3[64][320] = relu(A[64][160] @ W3T^T + b3) -> LDS bf16, XOR-swizzled (b64 writes).
// Stage 2: out[64][200] = h3 @ WTF^T + bFp -> float4 stores via rowmap; WTF fragments
//   prefetched 2-deep into registers, first two issued BEFORE the barrier (stage-1 acc dead).
// Swizzle: byte ^= (row&7)<<4 within each 640B row.

__global__ __launch_bounds__(256) void gemm3fc_kernel(
    const __hip_bfloat16* __restrict__ A,     // [N,160] bf16 (agg of h2)
    const __hip_bfloat16* __restrict__ W3T,   // [384,160] bf16
    const float* __restrict__ b3p,            // [384]
    const __hip_bfloat16* __restrict__ WTF,   // [256,320] bf16
    const float* __restrict__ bFp,            // [256]
    float* __restrict__ out,
    const int* __restrict__ rowmap) {
    __shared__ __align__(16) char h3[64 * 640];  // 40 KB
    const int tid = threadIdx.x;
    const int lane = tid & 63;
    const int w = tid >> 6;  // 0..3
    const int r0 = blockIdx.x * 64;
    const int frow = lane & 15;
    const int kq = lane >> 4;  // 0..3

    // ---- stage 1: 64 x 80 per wave ----
    {
        const __hip_bfloat16* ab[4];
        const __hip_bfloat16* bb[5];
#pragma unroll
        for (int m = 0; m < 4; ++m)
            ab[m] = A + (size_t)(r0 + m * 16 + frow) * 160 + kq * 8;
#pragma unroll
        for (int n = 0; n < 5; ++n)
            bb[n] = W3T + (size_t)(w * 80 + n * 16 + frow) * 160 + kq * 8;

        f32x4 acc[4][5];
#pragma unroll
        for (int m = 0; m < 4; ++m)
#pragma unroll
            for (int n = 0; n < 5; ++n) {
                f32x4 z = {0.0f, 0.0f, 0.0f, 0.0f};
                acc[m][n] = z;
            }
#pragma unroll
        for (int t = 0; t < 5; ++t) {
            short8 af[4], bfr[5];
#pragma unroll
            for (int m = 0; m < 4; ++m) af[m] = *(const short8*)(ab[m] + t * 32);
#pragma unroll
            for (int n = 0; n < 5; ++n) bfr[n] = *(const short8*)(bb[n] + t * 32);
#pragma unroll
            for (int m = 0; m < 4; ++m)
#pragma unroll
                for (int n = 0; n < 5; ++n)
                    acc[m][n] = __builtin_amdgcn_mfma_f32_16x16x32_bf16(bfr[n], af[m],
                                                                        acc[m][n], 0, 0, 0);
        }
        // relu+bias -> bf16x4 -> swizzled LDS (ds_write_b64)
#pragma unroll
        for (int m = 0; m < 4; ++m) {
            int row = m * 16 + frow;
            int swz = (row & 7) << 4;
#pragma unroll
            for (int n = 0; n < 5; ++n) {
                int col0 = w * 80 + n * 16 + (kq << 2);
                float4 bv = *(const float4*)(b3p + col0);
                ushort4 o;
                o.x = f2bfu(fmaxf(acc[m][n][0] + bv.x, 0.0f));
                o.y = f2bfu(fmaxf(acc[m][n][1] + bv.y, 0.0f));
                o.z = f2bfu(fmaxf(acc[m][n][2] + bv.z, 0.0f));
                o.w = f2bfu(fmaxf(acc[m][n][3] + bv.w, 0.0f));
                int byte = row * 640 + col0 * 2;
                *(ushort4*)(h3 + (byte ^ swz)) = o;
            }
        }
    }

    // stage-2 WTF pointers + 2-deep prefetch, issued BEFORE the barrier
    const __hip_bfloat16* bb2[4];
#pragma unroll
    for (int n = 0; n < 4; ++n)
        bb2[n] = WTF + (size_t)(w * 64 + n * 16 + frow) * 320 + kq * 8;
    short8 bfr2[2][4];
#pragma unroll
    for (int n = 0; n < 4; ++n) bfr2[0][n] = *(const short8*)(bb2[n]);
#pragma unroll
    for (int n = 0; n < 4; ++n) bfr2[1][n] = *(const short8*)(bb2[n] + 32);

    __syncthreads();

    // ---- stage 2: 64 x 64 per wave (cols w*64, guard <200), K=320 ----
    {
        int drow_[4];
#pragma unroll
        for (int m = 0; m < 4; ++m) drow_[m] = rowmap[r0 + m * 16 + frow];
        float4 bvF[4];
#pragma unroll
        for (int n = 0; n < 4; ++n)
            bvF[n] = *(const float4*)(bFp + (w * 64 + n * 16 + (kq << 2)));

        int abase[4], aswz[4];
#pragma unroll
        for (int m = 0; m < 4; ++m) {
            int row = m * 16 + frow;
            abase[m] = row * 640 + kq * 16;
            aswz[m] = (row & 7) << 4;
        }
        f32x4 acc[4][4];
#pragma unroll
        for (int m = 0; m < 4; ++m)
#pragma unroll
            for (int n = 0; n < 4; ++n) {
                f32x4 z = {0.0f, 0.0f, 0.0f, 0.0f};
                acc[m][n] = z;
            }
#pragma unroll
        for (int t = 0; t < 10; ++t) {
            short8 af[4];
#pragma unroll
            for (int m = 0; m < 4; ++m)
                af[m] = *(const short8*)(h3 + ((abase[m] + t * 64) ^ aswz[m]));
#pragma unroll
            for (int m = 0; m < 4; ++m)
#pragma unroll
                for (int n = 0; n < 4; ++n)
                    acc[m][n] = __builtin_amdgcn_mfma_f32_16x16x32_bf16(bfr2[t & 1][n], af[m],
                                                                        acc[m][n], 0, 0, 0);
            if (t + 2 < 10) {
#pragma unroll
                for (int n = 0; n < 4; ++n)
                    bfr2[t & 1][n] = *(const short8*)(bb2[n] + (t + 2) * 32);
            }
        }
        // epilogue: row = r0+m*16+(lane&15); col0 = w*64+n*16+kq*4; float4 stores
#pragma unroll
        for (int m = 0; m < 4; ++m) {
            int drow = drow_[m];
            if (drow < 0) continue;
#pragma unroll
            for (int n = 0; n < 4; ++n) {
                int col0 = w * 64 + n * 16 + (kq << 2);
                if (col0 >= 200) continue;
                float4 o;
                o.x = acc[m][n][0] + bvF[n].x;
                o.y = acc[m][n][1] + bvF[n].y;
                o.z = acc[m][n][2] + bvF[n].z;
                o.w = acc[m][n][3] + bvF[n].w;
                *(float4*)(out + (size_t)drow * 200 + col0) = o;
            }
        }
    }
}

// ---------------- launch ----------------

static inline char* align256(char* p) {
    return (char*)(((uintptr_t)p + 255) & ~(uintptr_t)255);
}

extern "C" void kernel_launch(void* const* d_in, const int* in_sizes, int n_in,
                              void* d_out, int out_size, void* d_ws, size_t ws_size,
                              hipStream_t stream) {
    const int N = N_NODES, E = N_EDGES;
    const float* x = (const float*)d_in[0];
    const int* ei = (const int*)d_in[1];
    const int* src = ei;
    const int* dst = ei + E;
    const int* batch = (const int*)d_in[2];
    const int* pmax = (const int*)d_in[3];
    const float* W1 = (const float*)d_in[4];
    const float* b1 = (const float*)d_in[5];
    const float* W2 = (const float*)d_in[6];
    const float* b2 = (const float*)d_in[7];
    const float* W3 = (const float*)d_in[8];
    const float* b3 = (const float*)d_in[9];
    const float* Wfc = (const float*)d_in[10];
    const float* bfc = (const float*)d_in[11];
    float* out = (float*)d_out;

    char* p = (char*)d_ws;
    float* dinv = (float*)p;          p = align256(p + (size_t)N * 4);
    int* deg = (int*)p;               p = align256(p + (size_t)N * 4);
    int* offs = (int*)p;              p = align256(p + (size_t)(N + 1) * 4);
    int* cursor = (int*)p;            p = align256(p + (size_t)N * 4);
    int* excl = (int*)p;              p = align256(p + (size_t)N * 4);
    int* bsum = (int*)p;              p = align256(p + 128 * 4);
    int* csr_src = (int*)p;           p = align256(p + (size_t)E * 4);
    float* csr_w = (float*)p;         p = align256(p + (size_t)E * 4);
    int* startb = (int*)p;            p = align256(p + (size_t)(N_GRAPHS + 1) * 4);
    int* rowmap = (int*)p;            p = align256(p + (size_t)N * 4);
    __hip_bfloat16* WT1 = (__hip_bfloat16*)p;  p = align256(p + 128 * 96 * 2);
    float* b1p = (float*)p;           p = align256(p + 128 * 4);
    __hip_bfloat16* WT2 = (__hip_bfloat16*)p;  p = align256(p + 256 * 96 * 2);
    float* b2p = (float*)p;           p = align256(p + 256 * 4);
    __hip_bfloat16* WT3 = (__hip_bfloat16*)p;  p = align256(p + 384 * 160 * 2);
    float* b3p = (float*)p;           p = align256(p + 384 * 4);
    __hip_bfloat16* WTF = (__hip_bfloat16*)p;  p = align256(p + 256 * 320 * 2);
    float* bFp = (float*)p;           p = align256(p + 256 * 4);
    __hip_bfloat16* bufAgg = (__hip_bfloat16*)p;  p = align256(p + (size_t)N * 320 * 2);
    __hip_bfloat16* bufH = (__hip_bfloat16*)p;    p = align256(p + (size_t)N * 320 * 2);

    // degree + CSR
    hipMemsetAsync(deg, 0, (size_t)N * 4, stream);
    deg_kernel<<<(E + 255) / 256, 256, 0, stream>>>(dst, deg);
    dinv_kernel<<<(N + 255) / 256, 256, 0, stream>>>(deg, dinv);
    scan1_kernel<<<100, 1024, 0, stream>>>(deg, excl, bsum);
    scan2_kernel<<<1, 128, 0, stream>>>(bsum);
    scan3_kernel<<<(N + 255) / 256, 256, 0, stream>>>(excl, bsum, offs, cursor);
    fill_kernel<<<(E + 255) / 256, 256, 0, stream>>>(src, dst, cursor, csr_src, csr_w, dinv);

    // dense-batch mapping
    start_kernel<<<(N + 255) / 256, 256, 0, stream>>>(batch, startb);
    rowmap_kernel<<<(N + 255) / 256, 256, 0, stream>>>(batch, startb, pmax, rowmap);

    // weight prep
    prep_w_kernel<<<(128 * 96 + 255) / 256, 256, 0, stream>>>(W1, b1, 78, 78, 96, 128, WT1, b1p);
    prep_w_kernel<<<(256 * 96 + 255) / 256, 256, 0, stream>>>(W2, b2, 78, 156, 96, 256, WT2, b2p);
    prep_w_kernel<<<(384 * 160 + 255) / 256, 256, 0, stream>>>(W3, b3, 156, 312, 160, 384, WT3, b3p);
    prep_w_kernel<<<(256 * 320 + 255) / 256, 256, 0, stream>>>(Wfc, bfc, 312, 200, 320, 256, WTF, bFp);

    // Layer 1: agg(x) -> [N,96]; gemm -> h1 [N,96]
    agg_f32_v3<<<(N * 24 + 255) / 256, 256, 0, stream>>>(x, offs, csr_src, csr_w, dinv, bufAgg);
    mfma_gemm_kernel<<<dim3(1, N / 128), 256, 0, stream>>>(
        bufAgg, 96, WT1, b1p, 3, bufH, 96, 96, nullptr, 1);

    // Layer 2: agg -> [N,96]; gemm -> h2 [N,160]
    agg_bf16_v3<96><<<(N * 12 + 255) / 256, 256, 0, stream>>>(bufH, offs, csr_src, csr_w, dinv, bufAgg);
    mfma_gemm_kernel<<<dim3(2, N / 128), 256, 0, stream>>>(
        bufAgg, 96, WT2, b2p, 3, bufH, 160, 160, nullptr, 1);

    // Layer 3 agg -> [N,160]; fused gemm3+FC (h3 never touches HBM)
    agg_bf16_v3<160><<<(N * 20 + 255) / 256, 256, 0, stream>>>(bufH, offs, csr_src, csr_w, dinv, bufAgg);
    padzero_kernel<<<dim3(25, N_GRAPHS), 256, 0, stream>>>(startb, out);
    gemm3fc_kernel<<<N / 64, 256, 0, stream>>>(bufAgg, WT3, b3p, WTF, bFp, out, rowmap);
}